// Round 1
// baseline (1104.625 us; speedup 1.0000x reference)
//
#include <hip/hip_runtime.h>

typedef unsigned short u16;
typedef unsigned int u32;
typedef __attribute__((ext_vector_type(4))) u16 u16x4;
typedef __attribute__((ext_vector_type(8))) u16 u16x8;
typedef __attribute__((ext_vector_type(4))) float f32x4;
typedef __attribute__((ext_vector_type(8))) __bf16 bf16x8;

#define DEV static __device__ __forceinline__

DEV u16 f2bf(float f) {
    u32 u = __builtin_bit_cast(u32, f);
    return (u16)((u + 0x7FFFu + ((u >> 16) & 1u)) >> 16);
}
DEV float bf2f(u16 h) { return __builtin_bit_cast(float, (u32)h << 16); }

DEV f32x4 mfma16(u16x8 a, u16x8 b, f32x4 c) {
    return __builtin_amdgcn_mfma_f32_16x16x32_bf16(
        __builtin_bit_cast(bf16x8, a), __builtin_bit_cast(bf16x8, b), c, 0, 0, 0);
}

// ---------------- elementwise converts ----------------

// xcomb[m][0:1024]=trend[m], xcomb[m][1024:2048]=detail[m], bf16.  4096x2048.
__global__ __launch_bounds__(256) void k_build_xcomb(
    const float* __restrict__ tr, const float* __restrict__ de, u16* __restrict__ out) {
    int i = blockIdx.x * 256 + threadIdx.x;     // 4096*512 threads, 4 elems each
    int m = i >> 9;
    int c = (i & 511) * 4;
    const float* src = (c < 1024) ? (tr + (size_t)m * 1024 + c)
                                  : (de + (size_t)m * 1024 + (c - 1024));
    f32x4 v = *(const f32x4*)src;
    u16x4 o = { f2bf(v[0]), f2bf(v[1]), f2bf(v[2]), f2bf(v[3]) };
    *(u16x4*)(out + (size_t)m * 2048 + c) = o;
}

__global__ __launch_bounds__(256) void k_convert(
    const float* __restrict__ in, u16* __restrict__ out, int n4) {
    int i = blockIdx.x * 256 + threadIdx.x;
    if (i >= n4) return;
    f32x4 v = ((const f32x4*)in)[i];
    u16x4 o = { f2bf(v[0]), f2bf(v[1]), f2bf(v[2]), f2bf(v[3]) };
    ((u16x4*)out)[i] = o;
}

// ---------------- transposes ----------------

// in: f32 R x C (row-major). out: bf16, out[c*ldo + r].
__global__ void k_transpose_f2b(const float* __restrict__ in, u16* __restrict__ out,
                                int R, int C, int ldo) {
    __shared__ float t[32][33];
    int c0 = blockIdx.x * 32, r0 = blockIdx.y * 32;
    int tx = threadIdx.x, ty = threadIdx.y;   // (32,8)
#pragma unroll
    for (int j = 0; j < 4; j++) {
        int r = r0 + ty + j * 8;
        t[ty + j * 8][tx] = in[(size_t)r * C + c0 + tx];
    }
    __syncthreads();
#pragma unroll
    for (int j = 0; j < 4; j++) {
        int c = c0 + ty + j * 8;
        out[(size_t)c * ldo + r0 + tx] = f2bf(t[tx][ty + j * 8]);
    }
}

// in: bf16 R x ldi (use C cols). out[c*ldo + r].
__global__ void k_transpose_b2b(const u16* __restrict__ in, int ldi,
                                u16* __restrict__ out, int ldo, int R, int C) {
    __shared__ u16 t[32][33];
    int c0 = blockIdx.x * 32, r0 = blockIdx.y * 32;
    int tx = threadIdx.x, ty = threadIdx.y;
#pragma unroll
    for (int j = 0; j < 4; j++)
        t[ty + j * 8][tx] = in[(size_t)(r0 + ty + j * 8) * ldi + c0 + tx];
    __syncthreads();
#pragma unroll
    for (int j = 0; j < 4; j++)
        out[(size_t)(c0 + ty + j * 8) * ldo + r0 + tx] = t[tx][ty + j * 8];
}

// ---------------- generic bf16 MFMA GEMM ----------------
// C[M x N] = A[M x K] (row-major, lda) @ Bt[N x K]^T (row-major, ldb=K) + bias
#define MODE_BF16 0
#define MODE_BF16_RELU 1
#define MODE_F32_GATED 2

__global__ __launch_bounds__(256) void k_gemm(
    const u16* __restrict__ A, int lda,
    const u16* __restrict__ Bt,
    int M, int N, int K,
    void* __restrict__ outp, int ldc, int mode,
    const float* __restrict__ bias1, const float* __restrict__ bias2,
    const float* __restrict__ gate) {
    __shared__ u16 As[128][40];
    __shared__ u16 Bs[128][40];
    const int tid = threadIdx.x, lane = tid & 63, wid = tid >> 6;
    const int l16 = lane & 15, l4 = lane >> 4;
    const int m0 = blockIdx.y * 128, n0 = blockIdx.x * 128;
    const int wm = (wid >> 1) * 64, wn = (wid & 1) * 64;
    f32x4 acc[4][4] = {};

    for (int k0 = 0; k0 < K; k0 += 32) {
#pragma unroll
        for (int i = 0; i < 2; i++) {
            int idx = tid + i * 256;           // 0..511
            int rr = idx >> 2, cc = (idx & 3) * 8;
            u16x8 va = {};
            int gr = m0 + rr;
            if (gr < M) va = *(const u16x8*)(A + (size_t)gr * lda + k0 + cc);
            *(u16x8*)&As[rr][cc] = va;
            u16x8 vb = {};
            int gn = n0 + rr;
            if (gn < N) vb = *(const u16x8*)(Bt + (size_t)gn * K + k0 + cc);
            *(u16x8*)&Bs[rr][cc] = vb;
        }
        __syncthreads();
        u16x8 af[4], bfr[4];
#pragma unroll
        for (int m = 0; m < 4; m++) af[m] = *(const u16x8*)&As[wm + m * 16 + l16][l4 * 8];
#pragma unroll
        for (int n = 0; n < 4; n++) bfr[n] = *(const u16x8*)&Bs[wn + n * 16 + l16][l4 * 8];
#pragma unroll
        for (int m = 0; m < 4; m++)
#pragma unroll
            for (int n = 0; n < 4; n++)
                acc[m][n] = mfma16(af[m], bfr[n], acc[m][n]);
        __syncthreads();
    }

#pragma unroll
    for (int m = 0; m < 4; m++) {
#pragma unroll
        for (int n = 0; n < 4; n++) {
            int col = n0 + wn + n * 16 + l16;
#pragma unroll
            for (int j = 0; j < 4; j++) {
                int row = m0 + wm + m * 16 + l4 * 4 + j;
                float v = acc[m][n][j];
                if (mode == MODE_F32_GATED) {
                    float g = gate[row];
                    ((float*)outp)[(size_t)row * ldc + col] =
                        v + g * bias1[col] + (1.f - g) * bias2[col];
                } else {
                    if (row < M) {
                        float bb = (bias2 != nullptr && col >= 1024) ? bias2[col - 1024]
                                                                     : bias1[col];
                        v += bb;
                        if (mode == MODE_BF16_RELU) v = fmaxf(v, 0.f);
                    } else {
                        v = 0.f;   // zero-pad rows M..Mpad (needed for K/V pad)
                    }
                    ((u16*)outp)[(size_t)row * ldc + col] = f2bf(v);
                }
            }
        }
    }
}

// ---------------- gate GEMV: sigmoid(h @ W2 + b2) ----------------
__global__ __launch_bounds__(256) void k_gate(const u16* __restrict__ h,
                                              const float* __restrict__ W2,
                                              const float* __restrict__ b2,
                                              float* __restrict__ gate) {
    int row = blockIdx.x * 4 + (threadIdx.x >> 6);
    int lane = threadIdx.x & 63;
    const u16* hp = h + (size_t)row * 1024 + lane * 16;
    u16x8 a = *(const u16x8*)hp;
    u16x8 b = *(const u16x8*)(hp + 8);
    const f32x4* wp = (const f32x4*)(W2 + lane * 16);
    f32x4 w0 = wp[0], w1 = wp[1], w2 = wp[2], w3 = wp[3];
    float s = 0.f;
#pragma unroll
    for (int i = 0; i < 4; i++) {
        s += bf2f(a[i]) * w0[i];
        s += bf2f(a[4 + i]) * w1[i];
        s += bf2f(b[i]) * w2[i];
        s += bf2f(b[4 + i]) * w3[i];
    }
#pragma unroll
    for (int d = 1; d < 64; d <<= 1) s += __shfl_xor(s, d);
    if (lane == 0) gate[row] = 1.f / (1.f + __expf(-(s + b2[0])));
}

// ---------------- fused flash cross-attention ----------------
// Q: 4096x1024 bf16; Kb: 1024(x ldk) padded rows zeroed; Vt: [h*64+e][s] 1024x1024
// out: bf16 into attn_comb (ldc 2048), scaled by gate (trend) or 1-gate (detail).
__global__ __launch_bounds__(256) void k_attn(
    const u16* __restrict__ Q,
    const u16* __restrict__ Kb, int ldk,
    const u16* __restrict__ Vt,
    const float* __restrict__ gate, int isTrend,
    u16* __restrict__ outp, int ocol) {
    __shared__ u16 Ks[64][72];
    __shared__ u16 Vs[64][72];
    __shared__ u16 Ps[4][32][72];
    const int tid = threadIdx.x, lane = tid & 63, wid = tid >> 6;
    const int l16 = lane & 15, l4 = lane >> 4;
    const int qt = blockIdx.x, bh = blockIdx.y;
    const int b = bh >> 4, h = bh & 15;
    const int row0 = b * 512 + qt * 128 + wid * 32;

    u16x8 qf[2][2];
#pragma unroll
    for (int m = 0; m < 2; m++)
#pragma unroll
        for (int kc = 0; kc < 2; kc++)
            qf[m][kc] = *(const u16x8*)(Q + (size_t)(row0 + m * 16 + l16) * 1024 +
                                        h * 64 + kc * 32 + l4 * 8);

    float runm[2][4], runl[2][4];
#pragma unroll
    for (int m = 0; m < 2; m++)
#pragma unroll
        for (int j = 0; j < 4; j++) { runm[m][j] = -3.0e38f; runl[m][j] = 0.f; }
    f32x4 oacc[2][4] = {};

    for (int st = 0; st < 16; st++) {
        const int s0 = st * 64;
#pragma unroll
        for (int i = 0; i < 2; i++) {
            int idx = tid + i * 256;
            int rr = idx >> 3, cc = (idx & 7) * 8;
            *(u16x8*)&Ks[rr][cc] = *(const u16x8*)(Kb + (size_t)(s0 + rr) * ldk + h * 64 + cc);
            *(u16x8*)&Vs[rr][cc] = *(const u16x8*)(Vt + (size_t)(h * 64 + rr) * 1024 + s0 + cc);
        }
        __syncthreads();

        // scores = Q Kt  (A=Q frag, B=K rows)
        f32x4 sa[2][4] = {};
#pragma unroll
        for (int n = 0; n < 4; n++) {
#pragma unroll
            for (int kc = 0; kc < 2; kc++) {
                u16x8 kf = *(const u16x8*)&Ks[n * 16 + l16][kc * 32 + l4 * 8];
#pragma unroll
                for (int m = 0; m < 2; m++) sa[m][n] = mfma16(qf[m][kc], kf, sa[m][n]);
            }
        }
        // scale + tail mask (s >= 1000)
#pragma unroll
        for (int m = 0; m < 2; m++)
#pragma unroll
            for (int n = 0; n < 4; n++) {
                bool valid = (s0 + n * 16 + l16) < 1000;
#pragma unroll
                for (int j = 0; j < 4; j++)
                    sa[m][n][j] = valid ? sa[m][n][j] * 0.125f : -3.0e38f;
            }
        // online softmax (rows spread over n-frags + lane&15)
#pragma unroll
        for (int m = 0; m < 2; m++) {
#pragma unroll
            for (int j = 0; j < 4; j++) {
                float rm = fmaxf(fmaxf(sa[m][0][j], sa[m][1][j]),
                                 fmaxf(sa[m][2][j], sa[m][3][j]));
#pragma unroll
                for (int d = 1; d < 16; d <<= 1) rm = fmaxf(rm, __shfl_xor(rm, d));
                float nm = fmaxf(runm[m][j], rm);
                float corr = __expf(runm[m][j] - nm);
                runm[m][j] = nm;
                float rs = 0.f;
#pragma unroll
                for (int n = 0; n < 4; n++) {
                    float p = __expf(sa[m][n][j] - nm);
                    sa[m][n][j] = p;
                    rs += p;
                }
#pragma unroll
                for (int d = 1; d < 16; d <<= 1) rs += __shfl_xor(rs, d);
                runl[m][j] = runl[m][j] * corr + rs;
#pragma unroll
                for (int n = 0; n < 4; n++) oacc[m][n][j] *= corr;
            }
        }
        // P -> LDS (wave-private), then PV
#pragma unroll
        for (int m = 0; m < 2; m++)
#pragma unroll
            for (int n = 0; n < 4; n++)
#pragma unroll
                for (int j = 0; j < 4; j++)
                    Ps[wid][m * 16 + l4 * 4 + j][n * 16 + l16] = f2bf(sa[m][n][j]);

        u16x8 pf[2][2];
#pragma unroll
        for (int m = 0; m < 2; m++)
#pragma unroll
            for (int kc = 0; kc < 2; kc++)
                pf[m][kc] = *(const u16x8*)&Ps[wid][m * 16 + l16][kc * 32 + l4 * 8];
#pragma unroll
        for (int ne = 0; ne < 4; ne++) {
#pragma unroll
            for (int kc = 0; kc < 2; kc++) {
                u16x8 vfr = *(const u16x8*)&Vs[ne * 16 + l16][kc * 32 + l4 * 8];
#pragma unroll
                for (int m = 0; m < 2; m++)
                    oacc[m][ne] = mfma16(pf[m][kc], vfr, oacc[m][ne]);
            }
        }
        __syncthreads();
    }

#pragma unroll
    for (int m = 0; m < 2; m++) {
#pragma unroll
        for (int j = 0; j < 4; j++) {
            int grow = row0 + m * 16 + l4 * 4 + j;
            float g = gate[grow];
            float wgt = isTrend ? g : (1.f - g);
            float f = wgt / runl[m][j];
#pragma unroll
            for (int ne = 0; ne < 4; ne++)
                outp[(size_t)grow * 2048 + ocol + h * 64 + ne * 16 + l16] =
                    f2bf(oacc[m][ne][j] * f);
        }
    }
}

// ---------------- launch ----------------

extern "C" void kernel_launch(void* const* d_in, const int* in_sizes, int n_in,
                              void* d_out, int out_size, void* d_ws, size_t ws_size,
                              hipStream_t stream) {
    (void)in_sizes; (void)n_in; (void)out_size; (void)ws_size;
    const float* trend  = (const float*)d_in[0];
    const float* detail = (const float*)d_in[1];
    const float* tproto = (const float*)d_in[2];
    const float* dproto = (const float*)d_in[3];
    const float* t_Wq = (const float*)d_in[4];
    const float* t_bq = (const float*)d_in[5];
    const float* t_Wk = (const float*)d_in[6];
    const float* t_bk = (const float*)d_in[7];
    const float* t_Wv = (const float*)d_in[8];
    const float* t_bv = (const float*)d_in[9];
    const float* t_Wo = (const float*)d_in[10];
    const float* t_bo = (const float*)d_in[11];
    const float* d_Wq = (const float*)d_in[12];
    const float* d_bq = (const float*)d_in[13];
    const float* d_Wk = (const float*)d_in[14];
    const float* d_bk = (const float*)d_in[15];
    const float* d_Wv = (const float*)d_in[16];
    const float* d_bv = (const float*)d_in[17];
    const float* d_Wo = (const float*)d_in[18];
    const float* d_bo = (const float*)d_in[19];
    const float* g_W1 = (const float*)d_in[20];
    const float* g_b1 = (const float*)d_in[21];
    const float* g_W2 = (const float*)d_in[22];
    const float* g_b2 = (const float*)d_in[23];

    char* w = (char*)d_ws;
    auto alloc = [&](size_t bytes) {
        char* p = w;
        w += (bytes + 255) & ~(size_t)255;
        return p;
    };
    u16* xcomb  = (u16*)alloc(4096ull * 2048 * 2);   // [trend|detail] bf16
    u16* pt     = (u16*)alloc(1000ull * 4096 * 2);
    u16* pd     = (u16*)alloc(1000ull * 4096 * 2);
    u16* WqTt   = (u16*)alloc(1024ull * 1024 * 2);
    u16* WqTd   = (u16*)alloc(1024ull * 1024 * 2);
    u16* WkvTt  = (u16*)alloc(2048ull * 4096 * 2);   // [WkT ; WvT], rows n, ld 4096
    u16* WkvTd  = (u16*)alloc(2048ull * 4096 * 2);
    u16* WoT    = (u16*)alloc(4096ull * 2048 * 2);   // rows n=4096, [WoT_t | WoT_d]
    u16* W1T    = (u16*)alloc(1024ull * 2048 * 2);
    u16* Qt     = (u16*)alloc(4096ull * 1024 * 2);
    u16* Qd     = (u16*)alloc(4096ull * 1024 * 2);
    u16* KVt    = (u16*)alloc(1024ull * 2048 * 2);   // [K | V], padded rows zeroed
    u16* KVd    = (u16*)alloc(1024ull * 2048 * 2);
    u16* VtT    = (u16*)alloc(1024ull * 1024 * 2);   // [h*64+e][s]
    u16* VdT    = (u16*)alloc(1024ull * 1024 * 2);
    u16* hbuf   = (u16*)alloc(4096ull * 1024 * 2);
    float* gateb = (float*)alloc(4096ull * 4);
    u16* attnc  = (u16*)alloc(4096ull * 2048 * 2);   // [g*At | (1-g)*Ad]

    dim3 tb(32, 8);

    // 1. converts
    k_build_xcomb<<<8192, 256, 0, stream>>>(trend, detail, xcomb);
    k_convert<<<4000, 256, 0, stream>>>(tproto, pt, 1024000);
    k_convert<<<4000, 256, 0, stream>>>(dproto, pd, 1024000);

    // 2. weight transposes (f32 KxN -> bf16 [n][k])
    k_transpose_f2b<<<dim3(32, 32), tb, 0, stream>>>(t_Wq, WqTt, 1024, 1024, 1024);
    k_transpose_f2b<<<dim3(32, 32), tb, 0, stream>>>(d_Wq, WqTd, 1024, 1024, 1024);
    k_transpose_f2b<<<dim3(32, 128), tb, 0, stream>>>(t_Wk, WkvTt, 4096, 1024, 4096);
    k_transpose_f2b<<<dim3(32, 128), tb, 0, stream>>>(t_Wv, WkvTt + 1024ull * 4096, 4096, 1024, 4096);
    k_transpose_f2b<<<dim3(32, 128), tb, 0, stream>>>(d_Wk, WkvTd, 4096, 1024, 4096);
    k_transpose_f2b<<<dim3(32, 128), tb, 0, stream>>>(d_Wv, WkvTd + 1024ull * 4096, 4096, 1024, 4096);
    k_transpose_f2b<<<dim3(128, 32), tb, 0, stream>>>(t_Wo, WoT, 1024, 4096, 2048);
    k_transpose_f2b<<<dim3(128, 32), tb, 0, stream>>>(d_Wo, WoT + 1024, 1024, 4096, 2048);
    k_transpose_f2b<<<dim3(32, 64), tb, 0, stream>>>(g_W1, W1T, 2048, 1024, 2048);

    // 3. gate MLP
    k_gemm<<<dim3(8, 32), 256, 0, stream>>>(xcomb, 2048, W1T, 4096, 1024, 2048,
                                            hbuf, 1024, MODE_BF16_RELU, g_b1, nullptr, nullptr);
    k_gate<<<1024, 256, 0, stream>>>(hbuf, g_W2, g_b2, gateb);

    // 4. Q projections
    k_gemm<<<dim3(8, 32), 256, 0, stream>>>(xcomb, 2048, WqTt, 4096, 1024, 1024,
                                            Qt, 1024, MODE_BF16, t_bq, nullptr, nullptr);
    k_gemm<<<dim3(8, 32), 256, 0, stream>>>(xcomb + 1024, 2048, WqTd, 4096, 1024, 1024,
                                            Qd, 1024, MODE_BF16, d_bq, nullptr, nullptr);

    // 5. K|V projections (M=1000 padded to 1024, zero pad rows)
    k_gemm<<<dim3(16, 8), 256, 0, stream>>>(pt, 4096, WkvTt, 1000, 2048, 4096,
                                            KVt, 2048, MODE_BF16, t_bk, t_bv, nullptr);
    k_gemm<<<dim3(16, 8), 256, 0, stream>>>(pd, 4096, WkvTd, 1000, 2048, 4096,
                                            KVd, 2048, MODE_BF16, d_bk, d_bv, nullptr);

    // 6. V transposes -> [h*64+e][s]
    k_transpose_b2b<<<dim3(32, 32), tb, 0, stream>>>(KVt + 1024, 2048, VtT, 1024, 1024, 1024);
    k_transpose_b2b<<<dim3(32, 32), tb, 0, stream>>>(KVd + 1024, 2048, VdT, 1024, 1024, 1024);

    // 7. fused attention (writes gate-scaled bf16 into attn_comb halves)
    k_attn<<<dim3(4, 128), 256, 0, stream>>>(Qt, KVt, 2048, VtT, gateb, 1, attnc, 0);
    k_attn<<<dim3(4, 128), 256, 0, stream>>>(Qd, KVd, 2048, VdT, gateb, 0, attnc, 1024);

    // 8. final gated output GEMM -> d_out (f32)
    k_gemm<<<dim3(32, 32), 256, 0, stream>>>(attnc, 2048, WoT, 4096, 4096, 2048,
                                             (float*)d_out, 4096, MODE_F32_GATED,
                                             t_bo, d_bo, gateb);
}

// Round 2
// 752.491 us; speedup vs baseline: 1.4680x; 1.4680x over previous
//
#include <hip/hip_runtime.h>

typedef unsigned short u16;
typedef unsigned int u32;
typedef __attribute__((ext_vector_type(4))) u16 u16x4;
typedef __attribute__((ext_vector_type(8))) u16 u16x8;
typedef __attribute__((ext_vector_type(4))) float f32x4;
typedef __attribute__((ext_vector_type(8))) __bf16 bf16x8;

#define DEV static __device__ __forceinline__

DEV u16 f2bf(float f) {
    u32 u = __builtin_bit_cast(u32, f);
    return (u16)((u + 0x7FFFu + ((u >> 16) & 1u)) >> 16);
}
DEV float bf2f(u16 h) { return __builtin_bit_cast(float, (u32)h << 16); }

DEV f32x4 mfma16(u16x8 a, u16x8 b, f32x4 c) {
    return __builtin_amdgcn_mfma_f32_16x16x32_bf16(
        __builtin_bit_cast(bf16x8, a), __builtin_bit_cast(bf16x8, b), c, 0, 0, 0);
}

// async global->LDS, 16B per lane; LDS dest = base + lane*16 (wave-uniform base)
DEV void gload16(const void* g, void* l) {
    __builtin_amdgcn_global_load_lds(
        (const __attribute__((address_space(1))) void*)g,
        (__attribute__((address_space(3))) void*)l, 16, 0, 0);
}

// ---------------- elementwise converts ----------------

__global__ __launch_bounds__(256) void k_build_xcomb(
    const float* __restrict__ tr, const float* __restrict__ de, u16* __restrict__ out) {
    int i = blockIdx.x * 256 + threadIdx.x;
    int m = i >> 9;
    int c = (i & 511) * 4;
    const float* src = (c < 1024) ? (tr + (size_t)m * 1024 + c)
                                  : (de + (size_t)m * 1024 + (c - 1024));
    f32x4 v = *(const f32x4*)src;
    u16x4 o = { f2bf(v[0]), f2bf(v[1]), f2bf(v[2]), f2bf(v[3]) };
    *(u16x4*)(out + (size_t)m * 2048 + c) = o;
}

__global__ __launch_bounds__(256) void k_convert(
    const float* __restrict__ in, u16* __restrict__ out, int n4) {
    int i = blockIdx.x * 256 + threadIdx.x;
    if (i >= n4) return;
    f32x4 v = ((const f32x4*)in)[i];
    u16x4 o = { f2bf(v[0]), f2bf(v[1]), f2bf(v[2]), f2bf(v[3]) };
    ((u16x4*)out)[i] = o;
}

// ---------------- transposes ----------------

__global__ void k_transpose_f2b(const float* __restrict__ in, u16* __restrict__ out,
                                int R, int C, int ldo) {
    __shared__ float t[32][33];
    int c0 = blockIdx.x * 32, r0 = blockIdx.y * 32;
    int tx = threadIdx.x, ty = threadIdx.y;   // (32,8)
#pragma unroll
    for (int j = 0; j < 4; j++)
        t[ty + j * 8][tx] = in[(size_t)(r0 + ty + j * 8) * C + c0 + tx];
    __syncthreads();
#pragma unroll
    for (int j = 0; j < 4; j++)
        out[(size_t)(c0 + ty + j * 8) * ldo + r0 + tx] = f2bf(t[tx][ty + j * 8]);
}

__global__ void k_transpose_b2b(const u16* __restrict__ in, int ldi,
                                u16* __restrict__ out, int ldo, int R, int C) {
    __shared__ u16 t[32][33];
    int c0 = blockIdx.x * 32, r0 = blockIdx.y * 32;
    int tx = threadIdx.x, ty = threadIdx.y;
#pragma unroll
    for (int j = 0; j < 4; j++)
        t[ty + j * 8][tx] = in[(size_t)(r0 + ty + j * 8) * ldi + c0 + tx];
    __syncthreads();
#pragma unroll
    for (int j = 0; j < 4; j++)
        out[(size_t)(c0 + ty + j * 8) * ldo + r0 + tx] = t[tx][ty + j * 8];
}

// ---------------- m97-style bf16 MFMA GEMM (128x128 tile, BK=32, gload_lds) --
// C[MxN] = A[MxK](lda) @ Bt[NxK]^T + bias.  M,N multiples of 128, K of 32.
// Bt row stride == K.  z-batched: blockIdx.z selects instance {0,1}.
#define MODE_BF16 0
#define MODE_BF16_RELU 1
#define MODE_F32_GATED 2

__global__ __launch_bounds__(256) void k_gemm128(
    const u16* __restrict__ A0, const u16* __restrict__ A1, int lda,
    const u16* __restrict__ B0, const u16* __restrict__ B1, int K,
    void* __restrict__ o0, void* __restrict__ o1, int ldc, int mode,
    const float* __restrict__ b1_0, const float* __restrict__ b1_1,
    const float* __restrict__ b2_0, const float* __restrict__ b2_1,
    const float* __restrict__ gate) {
    __shared__ u16 As[128 * 32];
    __shared__ u16 Bs[128 * 32];
    const int z = blockIdx.z;
    const u16* A = z ? A1 : A0;
    const u16* Bt = z ? B1 : B0;
    void* outp = z ? o1 : o0;
    const float* bias1 = z ? b1_1 : b1_0;
    const float* bias2 = z ? b2_1 : b2_0;

    const int tid = threadIdx.x, lane = tid & 63, wid = tid >> 6;
    const int l16 = lane & 15, l4 = lane >> 4;
    const int n0 = blockIdx.x * 128, m0 = blockIdx.y * 128;
    const int wm = (wid >> 1) * 64, wn = (wid & 1) * 64;

    // staging: wave w covers rows [w*32, w*32+32) of the 128-row tile
    const int srow = wid * 32 + (lane >> 2);
    const int scol = (lane & 3) * 8;
    const u16* gA = A + (size_t)(m0 + srow) * lda + scol;
    const u16* gB = Bt + (size_t)(n0 + srow) * (size_t)K + scol;
    u16* lA = As + wid * 32 * 32;
    u16* lB = Bs + wid * 32 * 32;

    f32x4 acc[4][4] = {};

    for (int k0 = 0; k0 < K; k0 += 32) {
        gload16(gA, lA);
        gload16(gA + (size_t)16 * lda, lA + 16 * 32);
        gload16(gB, lB);
        gload16(gB + (size_t)16 * K, lB + 16 * 32);
        gA += 32;
        gB += 32;
        __syncthreads();
        u16x8 af[4], bfr[4];
#pragma unroll
        for (int m = 0; m < 4; m++) af[m] = *(const u16x8*)&As[(wm + m * 16 + l16) * 32 + l4 * 8];
#pragma unroll
        for (int n = 0; n < 4; n++) bfr[n] = *(const u16x8*)&Bs[(wn + n * 16 + l16) * 32 + l4 * 8];
#pragma unroll
        for (int m = 0; m < 4; m++)
#pragma unroll
            for (int n = 0; n < 4; n++)
                acc[m][n] = mfma16(af[m], bfr[n], acc[m][n]);
        __syncthreads();
    }

#pragma unroll
    for (int m = 0; m < 4; m++) {
#pragma unroll
        for (int n = 0; n < 4; n++) {
            int col = n0 + wn + n * 16 + l16;
#pragma unroll
            for (int j = 0; j < 4; j++) {
                int row = m0 + wm + m * 16 + l4 * 4 + j;
                float v = acc[m][n][j];
                if (mode == MODE_F32_GATED) {
                    float g = gate[row];
                    ((float*)outp)[(size_t)row * ldc + col] =
                        v + g * bias1[col] + (1.f - g) * bias2[col];
                } else {
                    float bb = (bias2 != nullptr && col >= 1024) ? bias2[col - 1024]
                                                                 : bias1[col];
                    v += bb;
                    if (mode == MODE_BF16_RELU) v = fmaxf(v, 0.f);
                    ((u16*)outp)[(size_t)row * ldc + col] = f2bf(v);
                }
            }
        }
    }
}

// ---------------- gate GEMV: sigmoid(h @ W2 + b2) ----------------
__global__ __launch_bounds__(256) void k_gate(const u16* __restrict__ h,
                                              const float* __restrict__ W2,
                                              const float* __restrict__ b2,
                                              float* __restrict__ gate) {
    int row = blockIdx.x * 4 + (threadIdx.x >> 6);
    int lane = threadIdx.x & 63;
    const u16* hp = h + (size_t)row * 1024 + lane * 16;
    u16x8 a = *(const u16x8*)hp;
    u16x8 b = *(const u16x8*)(hp + 8);
    const f32x4* wp = (const f32x4*)(W2 + lane * 16);
    f32x4 w0 = wp[0], w1 = wp[1], w2 = wp[2], w3 = wp[3];
    float s = 0.f;
#pragma unroll
    for (int i = 0; i < 4; i++) {
        s += bf2f(a[i]) * w0[i];
        s += bf2f(a[4 + i]) * w1[i];
        s += bf2f(b[i]) * w2[i];
        s += bf2f(b[4 + i]) * w3[i];
    }
#pragma unroll
    for (int d = 1; d < 64; d <<= 1) s += __shfl_xor(s, d);
    if (lane == 0) gate[row] = 1.f / (1.f + __expf(-(s + b2[0])));
}

// ---------------- fused flash cross-attention ----------------
__global__ __launch_bounds__(256) void k_attn(
    const u16* __restrict__ Q,
    const u16* __restrict__ Kb, int ldk,
    const u16* __restrict__ Vt,
    const float* __restrict__ gate, int isTrend,
    u16* __restrict__ outp, int ocol) {
    __shared__ u16 Ks[64][72];
    __shared__ u16 Vs[64][72];
    __shared__ u16 Ps[4][32][72];
    const int tid = threadIdx.x, lane = tid & 63, wid = tid >> 6;
    const int l16 = lane & 15, l4 = lane >> 4;
    const int qt = blockIdx.x, bh = blockIdx.y;
    const int b = bh >> 4, h = bh & 15;
    const int row0 = b * 512 + qt * 128 + wid * 32;

    u16x8 qf[2][2];
#pragma unroll
    for (int m = 0; m < 2; m++)
#pragma unroll
        for (int kc = 0; kc < 2; kc++)
            qf[m][kc] = *(const u16x8*)(Q + (size_t)(row0 + m * 16 + l16) * 1024 +
                                        h * 64 + kc * 32 + l4 * 8);

    float runm[2][4], runl[2][4];
#pragma unroll
    for (int m = 0; m < 2; m++)
#pragma unroll
        for (int j = 0; j < 4; j++) { runm[m][j] = -3.0e38f; runl[m][j] = 0.f; }
    f32x4 oacc[2][4] = {};

    for (int st = 0; st < 16; st++) {
        const int s0 = st * 64;
#pragma unroll
        for (int i = 0; i < 2; i++) {
            int idx = tid + i * 256;
            int rr = idx >> 3, cc = (idx & 7) * 8;
            *(u16x8*)&Ks[rr][cc] = *(const u16x8*)(Kb + (size_t)(s0 + rr) * ldk + h * 64 + cc);
            *(u16x8*)&Vs[rr][cc] = *(const u16x8*)(Vt + (size_t)(h * 64 + rr) * 1024 + s0 + cc);
        }
        __syncthreads();

        f32x4 sa[2][4] = {};
#pragma unroll
        for (int n = 0; n < 4; n++) {
#pragma unroll
            for (int kc = 0; kc < 2; kc++) {
                u16x8 kf = *(const u16x8*)&Ks[n * 16 + l16][kc * 32 + l4 * 8];
#pragma unroll
                for (int m = 0; m < 2; m++) sa[m][n] = mfma16(qf[m][kc], kf, sa[m][n]);
            }
        }
#pragma unroll
        for (int m = 0; m < 2; m++)
#pragma unroll
            for (int n = 0; n < 4; n++) {
                bool valid = (s0 + n * 16 + l16) < 1000;
#pragma unroll
                for (int j = 0; j < 4; j++)
                    sa[m][n][j] = valid ? sa[m][n][j] * 0.125f : -3.0e38f;
            }
#pragma unroll
        for (int m = 0; m < 2; m++) {
#pragma unroll
            for (int j = 0; j < 4; j++) {
                float rm = fmaxf(fmaxf(sa[m][0][j], sa[m][1][j]),
                                 fmaxf(sa[m][2][j], sa[m][3][j]));
#pragma unroll
                for (int d = 1; d < 16; d <<= 1) rm = fmaxf(rm, __shfl_xor(rm, d));
                float nm = fmaxf(runm[m][j], rm);
                float corr = __expf(runm[m][j] - nm);
                runm[m][j] = nm;
                float rs = 0.f;
#pragma unroll
                for (int n = 0; n < 4; n++) {
                    float p = __expf(sa[m][n][j] - nm);
                    sa[m][n][j] = p;
                    rs += p;
                }
#pragma unroll
                for (int d = 1; d < 16; d <<= 1) rs += __shfl_xor(rs, d);
                runl[m][j] = runl[m][j] * corr + rs;
#pragma unroll
                for (int n = 0; n < 4; n++) oacc[m][n][j] *= corr;
            }
        }
#pragma unroll
        for (int m = 0; m < 2; m++)
#pragma unroll
            for (int n = 0; n < 4; n++)
#pragma unroll
                for (int j = 0; j < 4; j++)
                    Ps[wid][m * 16 + l4 * 4 + j][n * 16 + l16] = f2bf(sa[m][n][j]);

        u16x8 pf[2][2];
#pragma unroll
        for (int m = 0; m < 2; m++)
#pragma unroll
            for (int kc = 0; kc < 2; kc++)
                pf[m][kc] = *(const u16x8*)&Ps[wid][m * 16 + l16][kc * 32 + l4 * 8];
#pragma unroll
        for (int ne = 0; ne < 4; ne++) {
#pragma unroll
            for (int kc = 0; kc < 2; kc++) {
                u16x8 vfr = *(const u16x8*)&Vs[ne * 16 + l16][kc * 32 + l4 * 8];
#pragma unroll
                for (int m = 0; m < 2; m++)
                    oacc[m][ne] = mfma16(pf[m][kc], vfr, oacc[m][ne]);
            }
        }
        __syncthreads();
    }

#pragma unroll
    for (int m = 0; m < 2; m++) {
#pragma unroll
        for (int j = 0; j < 4; j++) {
            int grow = row0 + m * 16 + l4 * 4 + j;
            float g = gate[grow];
            float wgt = isTrend ? g : (1.f - g);
            float f = wgt / runl[m][j];
#pragma unroll
            for (int ne = 0; ne < 4; ne++)
                outp[(size_t)grow * 2048 + ocol + h * 64 + ne * 16 + l16] =
                    f2bf(oacc[m][ne][j] * f);
        }
    }
}

// ---------------- launch ----------------

extern "C" void kernel_launch(void* const* d_in, const int* in_sizes, int n_in,
                              void* d_out, int out_size, void* d_ws, size_t ws_size,
                              hipStream_t stream) {
    (void)in_sizes; (void)n_in; (void)out_size; (void)ws_size;
    const float* trend  = (const float*)d_in[0];
    const float* detail = (const float*)d_in[1];
    const float* tproto = (const float*)d_in[2];
    const float* dproto = (const float*)d_in[3];
    const float* t_Wq = (const float*)d_in[4];
    const float* t_bq = (const float*)d_in[5];
    const float* t_Wk = (const float*)d_in[6];
    const float* t_bk = (const float*)d_in[7];
    const float* t_Wv = (const float*)d_in[8];
    const float* t_bv = (const float*)d_in[9];
    const float* t_Wo = (const float*)d_in[10];
    const float* t_bo = (const float*)d_in[11];
    const float* d_Wq = (const float*)d_in[12];
    const float* d_bq = (const float*)d_in[13];
    const float* d_Wk = (const float*)d_in[14];
    const float* d_bk = (const float*)d_in[15];
    const float* d_Wv = (const float*)d_in[16];
    const float* d_bv = (const float*)d_in[17];
    const float* d_Wo = (const float*)d_in[18];
    const float* d_bo = (const float*)d_in[19];
    const float* g_W1 = (const float*)d_in[20];
    const float* g_b1 = (const float*)d_in[21];
    const float* g_W2 = (const float*)d_in[22];
    const float* g_b2 = (const float*)d_in[23];

    char* w = (char*)d_ws;
    auto alloc = [&](size_t bytes) {
        char* p = w;
        w += (bytes + 255) & ~(size_t)255;
        return p;
    };
    u16* xcomb  = (u16*)alloc(4096ull * 2048 * 2);   // [trend|detail] bf16
    u16* pt     = (u16*)alloc(1024ull * 4096 * 2);   // padded to 1024 rows
    u16* pd     = (u16*)alloc(1024ull * 4096 * 2);
    u16* WqTt   = (u16*)alloc(1024ull * 1024 * 2);
    u16* WqTd   = (u16*)alloc(1024ull * 1024 * 2);
    u16* WkvTt  = (u16*)alloc(2048ull * 4096 * 2);   // [WkT ; WvT], ld 4096
    u16* WkvTd  = (u16*)alloc(2048ull * 4096 * 2);
    u16* WoT    = (u16*)alloc(4096ull * 2048 * 2);   // [WoT_t | WoT_d], ld 2048
    u16* W1T    = (u16*)alloc(1024ull * 2048 * 2);
    u16* Qt     = (u16*)alloc(4096ull * 1024 * 2);
    u16* Qd     = (u16*)alloc(4096ull * 1024 * 2);
    u16* KVt    = (u16*)alloc(1024ull * 2048 * 2);   // [K | V]
    u16* KVd    = (u16*)alloc(1024ull * 2048 * 2);
    u16* VtT    = (u16*)alloc(1024ull * 1024 * 2);   // [h*64+e][s]
    u16* VdT    = (u16*)alloc(1024ull * 1024 * 2);
    u16* hbuf   = (u16*)alloc(4096ull * 1024 * 2);
    float* gateb = (float*)alloc(4096ull * 4);
    u16* attnc  = (u16*)alloc(4096ull * 2048 * 2);   // [g*At | (1-g)*Ad]

    dim3 tb(32, 8);

    // 1. converts (+ zero the proto pad rows 1000..1023)
    k_build_xcomb<<<8192, 256, 0, stream>>>(trend, detail, xcomb);
    k_convert<<<4000, 256, 0, stream>>>(tproto, pt, 1024000);
    k_convert<<<4000, 256, 0, stream>>>(dproto, pd, 1024000);
    hipMemsetAsync(pt + 1000ull * 4096, 0, 24ull * 4096 * 2, stream);
    hipMemsetAsync(pd + 1000ull * 4096, 0, 24ull * 4096 * 2, stream);

    // 2. weight transposes (f32 KxN -> bf16 [n][k])
    k_transpose_f2b<<<dim3(32, 32), tb, 0, stream>>>(t_Wq, WqTt, 1024, 1024, 1024);
    k_transpose_f2b<<<dim3(32, 32), tb, 0, stream>>>(d_Wq, WqTd, 1024, 1024, 1024);
    k_transpose_f2b<<<dim3(32, 128), tb, 0, stream>>>(t_Wk, WkvTt, 4096, 1024, 4096);
    k_transpose_f2b<<<dim3(32, 128), tb, 0, stream>>>(t_Wv, WkvTt + 1024ull * 4096, 4096, 1024, 4096);
    k_transpose_f2b<<<dim3(32, 128), tb, 0, stream>>>(d_Wk, WkvTd, 4096, 1024, 4096);
    k_transpose_f2b<<<dim3(32, 128), tb, 0, stream>>>(d_Wv, WkvTd + 1024ull * 4096, 4096, 1024, 4096);
    k_transpose_f2b<<<dim3(128, 32), tb, 0, stream>>>(t_Wo, WoT, 1024, 4096, 2048);
    k_transpose_f2b<<<dim3(128, 32), tb, 0, stream>>>(d_Wo, WoT + 1024, 1024, 4096, 2048);
    k_transpose_f2b<<<dim3(32, 64), tb, 0, stream>>>(g_W1, W1T, 2048, 1024, 2048);

    // 3. gate MLP  (M=4096,N=1024,K=2048)
    k_gemm128<<<dim3(8, 32, 1), 256, 0, stream>>>(
        xcomb, nullptr, 2048, W1T, nullptr, 2048, hbuf, nullptr, 1024,
        MODE_BF16_RELU, g_b1, nullptr, nullptr, nullptr, nullptr);
    k_gate<<<1024, 256, 0, stream>>>(hbuf, g_W2, g_b2, gateb);

    // 4. Q projections, z-batched  (M=4096,N=1024,K=1024)
    k_gemm128<<<dim3(8, 32, 2), 256, 0, stream>>>(
        xcomb, xcomb + 1024, 2048, WqTt, WqTd, 1024, Qt, Qd, 1024,
        MODE_BF16, t_bq, d_bq, nullptr, nullptr, nullptr);

    // 5. K|V projections, z-batched  (M=1024 padded, N=2048, K=4096)
    k_gemm128<<<dim3(16, 8, 2), 256, 0, stream>>>(
        pt, pd, 4096, WkvTt, WkvTd, 4096, KVt, KVd, 2048,
        MODE_BF16, t_bk, d_bk, t_bv, d_bv, nullptr);

    // 6. V transposes -> [h*64+e][s]
    k_transpose_b2b<<<dim3(32, 32), tb, 0, stream>>>(KVt + 1024, 2048, VtT, 1024, 1024, 1024);
    k_transpose_b2b<<<dim3(32, 32), tb, 0, stream>>>(KVd + 1024, 2048, VdT, 1024, 1024, 1024);

    // 7. fused attention (gate-scaled bf16 into attn_comb halves)
    k_attn<<<dim3(4, 128), 256, 0, stream>>>(Qt, KVt, 2048, VtT, gateb, 1, attnc, 0);
    k_attn<<<dim3(4, 128), 256, 0, stream>>>(Qd, KVd, 2048, VdT, gateb, 0, attnc, 1024);

    // 8. final gated output GEMM -> d_out (f32)  (M=4096,N=4096,K=2048)
    k_gemm128<<<dim3(32, 32, 1), 256, 0, stream>>>(
        attnc, nullptr, 2048, WoT, nullptr, 2048, (float*)d_out, nullptr, 4096,
        MODE_F32_GATED, t_bo, nullptr, d_bo, nullptr, gateb);
}

// Round 3
// 646.973 us; speedup vs baseline: 1.7074x; 1.1631x over previous
//
#include <hip/hip_runtime.h>

typedef unsigned short u16;
typedef unsigned int u32;
typedef __attribute__((ext_vector_type(4))) u16 u16x4;
typedef __attribute__((ext_vector_type(8))) u16 u16x8;
typedef __attribute__((ext_vector_type(4))) float f32x4;
typedef __attribute__((ext_vector_type(8))) __bf16 bf16x8;

#define DEV static __device__ __forceinline__

DEV u16 f2bf(float f) {
    u32 u = __builtin_bit_cast(u32, f);
    return (u16)((u + 0x7FFFu + ((u >> 16) & 1u)) >> 16);
}
DEV float bf2f(u16 h) { return __builtin_bit_cast(float, (u32)h << 16); }

DEV f32x4 mfma16(u16x8 a, u16x8 b, f32x4 c) {
    return __builtin_amdgcn_mfma_f32_16x16x32_bf16(
        __builtin_bit_cast(bf16x8, a), __builtin_bit_cast(bf16x8, b), c, 0, 0, 0);
}

// async global->LDS, 16B/lane; LDS dest = wave-uniform base + lane*16
DEV void gload16(const void* g, void* l) {
    __builtin_amdgcn_global_load_lds(
        (const __attribute__((address_space(1))) void*)g,
        (__attribute__((address_space(3))) void*)l, 16, 0, 0);
}

// ---------------- elementwise converts ----------------

__global__ __launch_bounds__(256) void k_build_xcomb(
    const float* __restrict__ tr, const float* __restrict__ de, u16* __restrict__ out) {
    int i = blockIdx.x * 256 + threadIdx.x;
    int m = i >> 9;
    int c = (i & 511) * 4;
    const float* src = (c < 1024) ? (tr + (size_t)m * 1024 + c)
                                  : (de + (size_t)m * 1024 + (c - 1024));
    f32x4 v = *(const f32x4*)src;
    u16x4 o = { f2bf(v[0]), f2bf(v[1]), f2bf(v[2]), f2bf(v[3]) };
    *(u16x4*)(out + (size_t)m * 2048 + c) = o;
}

__global__ __launch_bounds__(256) void k_convert(
    const float* __restrict__ in, u16* __restrict__ out, int n4) {
    int i = blockIdx.x * 256 + threadIdx.x;
    if (i >= n4) return;
    f32x4 v = ((const f32x4*)in)[i];
    u16x4 o = { f2bf(v[0]), f2bf(v[1]), f2bf(v[2]), f2bf(v[3]) };
    ((u16x4*)out)[i] = o;
}

// ---------------- transposes ----------------

__global__ void k_transpose_f2b(const float* __restrict__ in, u16* __restrict__ out,
                                int R, int C, int ldo) {
    __shared__ float t[32][33];
    int c0 = blockIdx.x * 32, r0 = blockIdx.y * 32;
    int tx = threadIdx.x, ty = threadIdx.y;   // (32,8)
#pragma unroll
    for (int j = 0; j < 4; j++)
        t[ty + j * 8][tx] = in[(size_t)(r0 + ty + j * 8) * C + c0 + tx];
    __syncthreads();
#pragma unroll
    for (int j = 0; j < 4; j++)
        out[(size_t)(c0 + ty + j * 8) * ldo + r0 + tx] = f2bf(t[tx][ty + j * 8]);
}

__global__ void k_transpose_b2b(const u16* __restrict__ in, int ldi,
                                u16* __restrict__ out, int ldo, int R, int C) {
    __shared__ u16 t[32][33];
    int c0 = blockIdx.x * 32, r0 = blockIdx.y * 32;
    int tx = threadIdx.x, ty = threadIdx.y;
#pragma unroll
    for (int j = 0; j < 4; j++)
        t[ty + j * 8][tx] = in[(size_t)(r0 + ty + j * 8) * ldi + c0 + tx];
    __syncthreads();
#pragma unroll
    for (int j = 0; j < 4; j++)
        out[(size_t)(c0 + ty + j * 8) * ldo + r0 + tx] = t[tx][ty + j * 8];
}

// ---------------- m97-style 128x128 GEMM (z-batched via struct) ----------------
#define MODE_BF16 0
#define MODE_BF16_RELU 1

struct GemmArgs {
    const u16* A[3];
    const u16* B[3];
    u16* o[3];
    const float* bias1[3];
    const float* bias2[3];
    int K[3];
    int lda[3];
    int ldc[3];
    int mode[3];
};

__global__ __launch_bounds__(256) void k_gemm128(GemmArgs ga) {
    __shared__ u16 As[128 * 32];
    __shared__ u16 Bs[128 * 32];
    const int z = blockIdx.z;
    const u16* A = ga.A[z];
    const u16* Bt = ga.B[z];
    u16* outp = ga.o[z];
    const float* bias1 = ga.bias1[z];
    const float* bias2 = ga.bias2[z];
    const int K = ga.K[z], lda = ga.lda[z], ldc = ga.ldc[z], mode = ga.mode[z];

    const int tid = threadIdx.x, lane = tid & 63, wid = tid >> 6;
    const int l16 = lane & 15, l4 = lane >> 4;
    const int n0 = blockIdx.x * 128, m0 = blockIdx.y * 128;
    const int wm = (wid >> 1) * 64, wn = (wid & 1) * 64;

    const int srow = wid * 32 + (lane >> 2);
    const int scol = (lane & 3) * 8;
    const u16* gA = A + (size_t)(m0 + srow) * lda + scol;
    const u16* gB = Bt + (size_t)(n0 + srow) * (size_t)K + scol;
    u16* lA = As + wid * 32 * 32;
    u16* lB = Bs + wid * 32 * 32;

    f32x4 acc[4][4] = {};

    for (int k0 = 0; k0 < K; k0 += 32) {
        gload16(gA, lA);
        gload16(gA + (size_t)16 * lda, lA + 16 * 32);
        gload16(gB, lB);
        gload16(gB + (size_t)16 * K, lB + 16 * 32);
        gA += 32;
        gB += 32;
        __syncthreads();
        u16x8 af[4], bfr[4];
#pragma unroll
        for (int m = 0; m < 4; m++) af[m] = *(const u16x8*)&As[(wm + m * 16 + l16) * 32 + l4 * 8];
#pragma unroll
        for (int n = 0; n < 4; n++) bfr[n] = *(const u16x8*)&Bs[(wn + n * 16 + l16) * 32 + l4 * 8];
#pragma unroll
        for (int m = 0; m < 4; m++)
#pragma unroll
            for (int n = 0; n < 4; n++)
                acc[m][n] = mfma16(af[m], bfr[n], acc[m][n]);
        __syncthreads();
    }

#pragma unroll
    for (int m = 0; m < 4; m++) {
#pragma unroll
        for (int n = 0; n < 4; n++) {
            int col = n0 + wn + n * 16 + l16;
#pragma unroll
            for (int j = 0; j < 4; j++) {
                int row = m0 + wm + m * 16 + l4 * 4 + j;
                float v = acc[m][n][j];
                float bb = (bias2 != nullptr && col >= 1024) ? bias2[col - 1024] : bias1[col];
                v += bb;
                if (mode == MODE_BF16_RELU) v = fmaxf(v, 0.f);
                outp[(size_t)row * ldc + col] = f2bf(v);
            }
        }
    }
}

// ---------------- 256^2 8-phase GEMM, gated f32 epilogue ----------------
// C[M x N] f32 = A[M x K]bf16 @ Bt[N x K]^T bf16, C += g*bias1 + (1-g)*bias2.
// M,N multiples of 256; K multiple of 64. Grid (N/256, M/256), 512 threads.
// Schedule: per K-tile (BK=64) 4 quadrant-phases; each phase:
//   {ds_read frags | issue 1 half-tile (2x gload_lds) | bar | setprio1 16xMFMA setprio0 | bar}
// counted vmcnt(4) once per tile (allowed leftover = next tile's B half-loads).
// LDS: 2 bufs x (A 256x64 + B 256x64) bf16 = 128 KiB, XOR-swizzled (both sides).
__global__ __launch_bounds__(512, 2) void k_gemm256g(
    const u16* __restrict__ A, int ldaE,
    const u16* __restrict__ Bt, int ldbE,
    int K,
    float* __restrict__ C, int ldcE,
    const float* __restrict__ bias1, const float* __restrict__ bias2,
    const float* __restrict__ gate) {
    __shared__ __attribute__((aligned(16))) u16 sm[2 * 32768];  // 128 KiB
    char* smc = (char*)sm;

    const int tid = threadIdx.x, lane = tid & 63, wid = tid >> 6;
    const int l16 = lane & 15, l4 = lane >> 4;
    const int wm = (wid >> 2) * 128;      // wave M-row: 2 rows of waves
    const int wn = (wid & 3) * 64;        // wave N-col: 4 cols of waves
    const int m0 = blockIdx.y * 256, n0 = blockIdx.x * 256;

    // per-lane staging source offsets (issue 0: rows 0-63, issue 1: rows 64-127 of a half)
    const int p0 = wid * 1024 + lane * 16;
    const int p1 = p0 + 8192;
    const int rr0 = p0 >> 7, rr1 = p1 >> 7;
    const int cb0 = (p0 & 127) ^ ((rr0 & 7) << 4);   // inverse-swizzled source col
    const int cb1 = (p1 & 127) ^ ((rr1 & 7) << 4);
    const size_t ldaB = (size_t)ldaE * 2, ldbB = (size_t)ldbE * 2;
    const char* Ab = (const char*)A;
    const char* Bb = (const char*)Bt;
    const size_t aOff0 = (size_t)(m0 + rr0) * ldaB + cb0;
    const size_t aOff1 = (size_t)(m0 + rr1) * ldaB + cb1;
    const size_t bOff0 = (size_t)(n0 + rr0) * ldbB + cb0;
    const size_t bOff1 = (size_t)(n0 + rr1) * ldbB + cb1;

    auto stageA = [&](int T, int h) {
        size_t tOff = (size_t)T * 128 + (size_t)h * 128 * ldaB;
        char* d = smc + (T & 1) * 65536 + h * 16384 + wid * 1024;
        gload16(Ab + aOff0 + tOff, d);
        gload16(Ab + aOff1 + tOff, d + 8192);
    };
    auto stageB = [&](int T, int h) {
        size_t tOff = (size_t)T * 128 + (size_t)h * 128 * ldbB;
        char* d = smc + (T & 1) * 65536 + 32768 + h * 16384 + wid * 1024;
        gload16(Bb + bOff0 + tOff, d);
        gload16(Bb + bOff1 + tOff, d + 8192);
    };
    auto readA = [&](int buf, int mf, int kc) -> u16x8 {
        int row = wm + mf * 16 + l16;
        int cb = (kc * 64 + l4 * 16) ^ ((l16 & 7) << 4);
        return *(const u16x8*)(smc + buf * 65536 + row * 128 + cb);
    };
    auto readB = [&](int buf, int nf, int kc) -> u16x8 {
        int row = wn + nf * 16 + l16;
        int cb = (kc * 64 + l4 * 16) ^ ((l16 & 7) << 4);
        return *(const u16x8*)(smc + buf * 65536 + 32768 + row * 128 + cb);
    };

    f32x4 acc[8][4] = {};
    const int NT = K >> 6;

    // prologue: tile0 (A+B) -> buf0, tile1 B -> buf1. A(1) staged in iter 0.
    stageA(0, 0); stageA(0, 1);
    stageB(0, 0); stageB(0, 1);
    stageB(1, 0); stageB(1, 1);
    asm volatile("s_waitcnt vmcnt(4)" ::: "memory");   // tile0 landed (B(1) may fly)
    __builtin_amdgcn_s_barrier();

    for (int t = 0; t < NT; ++t) {
        const int buf = t & 1;
        u16x8 bfr[4][2];
#pragma unroll
        for (int q = 0; q < 4; ++q) {
            u16x8 af[2][2];
            if (q == 0) {
#pragma unroll
                for (int nf = 0; nf < 4; nf++)
#pragma unroll
                    for (int kc = 0; kc < 2; kc++) bfr[nf][kc] = readB(buf, nf, kc);
            }
#pragma unroll
            for (int im = 0; im < 2; im++)
#pragma unroll
                for (int kc = 0; kc < 2; kc++) af[im][kc] = readA(buf, 2 * q + im, kc);

            // stage one half-tile: A halves of t+1 (into buf^1, freed last iter),
            // B halves of t+2 (into buf, freed after this iter's q0 barrier).
            if (q == 0) { if (t + 1 < NT) stageA(t + 1, 0); }
            else if (q == 1) { if (t + 1 < NT) stageA(t + 1, 1); }
            else if (q == 2) { if (t + 2 < NT) stageB(t + 2, 0); }
            else { if (t + 2 < NT) stageB(t + 2, 1); }

            asm volatile("" ::: "memory");
            __builtin_amdgcn_s_barrier();
            __builtin_amdgcn_s_setprio(1);
#pragma unroll
            for (int im = 0; im < 2; im++)
#pragma unroll
                for (int nf = 0; nf < 4; nf++)
#pragma unroll
                    for (int kc = 0; kc < 2; kc++)
                        acc[2 * q + im][nf] = mfma16(af[im][kc], bfr[nf][kc], acc[2 * q + im][nf]);
            __builtin_amdgcn_s_setprio(0);
            asm volatile("" ::: "memory");
            if (q == 3) {
                // entering tile t+1: its A (issued this iter) must land;
                // allowed leftover = B(t+2) half-loads (4) if staged.
                if (t + 2 < NT) asm volatile("s_waitcnt vmcnt(4)" ::: "memory");
                else            asm volatile("s_waitcnt vmcnt(0)" ::: "memory");
            }
            __builtin_amdgcn_s_barrier();
        }
    }

    // epilogue: gated dual-bias f32 write
#pragma unroll
    for (int mf = 0; mf < 8; mf++) {
#pragma unroll
        for (int j = 0; j < 4; j++) {
            int row = m0 + wm + mf * 16 + l4 * 4 + j;
            float g = gate[row];
#pragma unroll
            for (int nf = 0; nf < 4; nf++) {
                int col = n0 + wn + nf * 16 + l16;
                C[(size_t)row * ldcE + col] =
                    acc[mf][nf][j] + g * bias1[col] + (1.f - g) * bias2[col];
            }
        }
    }
}

// ---------------- gate GEMV: sigmoid(h @ W2 + b2) ----------------
__global__ __launch_bounds__(256) void k_gate(const u16* __restrict__ h,
                                              const float* __restrict__ W2,
                                              const float* __restrict__ b2,
                                              float* __restrict__ gate) {
    int row = blockIdx.x * 4 + (threadIdx.x >> 6);
    int lane = threadIdx.x & 63;
    const u16* hp = h + (size_t)row * 1024 + lane * 16;
    u16x8 a = *(const u16x8*)hp;
    u16x8 b = *(const u16x8*)(hp + 8);
    const f32x4* wp = (const f32x4*)(W2 + lane * 16);
    f32x4 w0 = wp[0], w1 = wp[1], w2 = wp[2], w3 = wp[3];
    float s = 0.f;
#pragma unroll
    for (int i = 0; i < 4; i++) {
        s += bf2f(a[i]) * w0[i];
        s += bf2f(a[4 + i]) * w1[i];
        s += bf2f(b[i]) * w2[i];
        s += bf2f(b[4 + i]) * w3[i];
    }
#pragma unroll
    for (int d = 1; d < 64; d <<= 1) s += __shfl_xor(s, d);
    if (lane == 0) gate[row] = 1.f / (1.f + __expf(-(s + b2[0])));
}

// ---------------- fused flash cross-attention (z-batched) ----------------
__global__ __launch_bounds__(256) void k_attn(
    const u16* __restrict__ Q0, const u16* __restrict__ Q1,
    const u16* __restrict__ KV0, const u16* __restrict__ KV1, int ldk,
    const u16* __restrict__ Vt0, const u16* __restrict__ Vt1,
    const float* __restrict__ gate,
    u16* __restrict__ outp) {
    __shared__ u16 Ks[64][72];
    __shared__ u16 Vs[64][72];
    __shared__ u16 Ps[4][32][72];
    const int z = blockIdx.z;
    const u16* Q = z ? Q1 : Q0;
    const u16* Kb = z ? KV1 : KV0;
    const u16* Vt = z ? Vt1 : Vt0;
    const int isTrend = (z == 0);
    const int ocol = z * 1024;

    const int tid = threadIdx.x, lane = tid & 63, wid = tid >> 6;
    const int l16 = lane & 15, l4 = lane >> 4;
    const int qt = blockIdx.x, bh = blockIdx.y;
    const int b = bh >> 4, h = bh & 15;
    const int row0 = b * 512 + qt * 128 + wid * 32;

    u16x8 qf[2][2];
#pragma unroll
    for (int m = 0; m < 2; m++)
#pragma unroll
        for (int kc = 0; kc < 2; kc++)
            qf[m][kc] = *(const u16x8*)(Q + (size_t)(row0 + m * 16 + l16) * 1024 +
                                        h * 64 + kc * 32 + l4 * 8);

    float runm[2][4], runl[2][4];
#pragma unroll
    for (int m = 0; m < 2; m++)
#pragma unroll
        for (int j = 0; j < 4; j++) { runm[m][j] = -3.0e38f; runl[m][j] = 0.f; }
    f32x4 oacc[2][4] = {};

    for (int st = 0; st < 16; st++) {
        const int s0 = st * 64;
#pragma unroll
        for (int i = 0; i < 2; i++) {
            int idx = tid + i * 256;
            int rr = idx >> 3, cc = (idx & 7) * 8;
            *(u16x8*)&Ks[rr][cc] = *(const u16x8*)(Kb + (size_t)(s0 + rr) * ldk + h * 64 + cc);
            *(u16x8*)&Vs[rr][cc] = *(const u16x8*)(Vt + (size_t)(h * 64 + rr) * 1024 + s0 + cc);
        }
        __syncthreads();

        f32x4 sa[2][4] = {};
#pragma unroll
        for (int n = 0; n < 4; n++) {
#pragma unroll
            for (int kc = 0; kc < 2; kc++) {
                u16x8 kf = *(const u16x8*)&Ks[n * 16 + l16][kc * 32 + l4 * 8];
#pragma unroll
                for (int m = 0; m < 2; m++) sa[m][n] = mfma16(qf[m][kc], kf, sa[m][n]);
            }
        }
#pragma unroll
        for (int m = 0; m < 2; m++)
#pragma unroll
            for (int n = 0; n < 4; n++) {
                bool valid = (s0 + n * 16 + l16) < 1000;
#pragma unroll
                for (int j = 0; j < 4; j++)
                    sa[m][n][j] = valid ? sa[m][n][j] * 0.125f : -3.0e38f;
            }
#pragma unroll
        for (int m = 0; m < 2; m++) {
#pragma unroll
            for (int j = 0; j < 4; j++) {
                float rm = fmaxf(fmaxf(sa[m][0][j], sa[m][1][j]),
                                 fmaxf(sa[m][2][j], sa[m][3][j]));
#pragma unroll
                for (int d = 1; d < 16; d <<= 1) rm = fmaxf(rm, __shfl_xor(rm, d));
                float nm = fmaxf(runm[m][j], rm);
                float corr = __expf(runm[m][j] - nm);
                runm[m][j] = nm;
                float rs = 0.f;
#pragma unroll
                for (int n = 0; n < 4; n++) {
                    float p = __expf(sa[m][n][j] - nm);
                    sa[m][n][j] = p;
                    rs += p;
                }
#pragma unroll
                for (int d = 1; d < 16; d <<= 1) rs += __shfl_xor(rs, d);
                runl[m][j] = runl[m][j] * corr + rs;
#pragma unroll
                for (int n = 0; n < 4; n++) oacc[m][n][j] *= corr;
            }
        }
#pragma unroll
        for (int m = 0; m < 2; m++)
#pragma unroll
            for (int n = 0; n < 4; n++)
#pragma unroll
                for (int j = 0; j < 4; j++)
                    Ps[wid][m * 16 + l4 * 4 + j][n * 16 + l16] = f2bf(sa[m][n][j]);

        u16x8 pf[2][2];
#pragma unroll
        for (int m = 0; m < 2; m++)
#pragma unroll
            for (int kc = 0; kc < 2; kc++)
                pf[m][kc] = *(const u16x8*)&Ps[wid][m * 16 + l16][kc * 32 + l4 * 8];
#pragma unroll
        for (int ne = 0; ne < 4; ne++) {
#pragma unroll
            for (int kc = 0; kc < 2; kc++) {
                u16x8 vfr = *(const u16x8*)&Vs[ne * 16 + l16][kc * 32 + l4 * 8];
#pragma unroll
                for (int m = 0; m < 2; m++)
                    oacc[m][ne] = mfma16(pf[m][kc], vfr, oacc[m][ne]);
            }
        }
        __syncthreads();
    }

#pragma unroll
    for (int m = 0; m < 2; m++) {
#pragma unroll
        for (int j = 0; j < 4; j++) {
            int grow = row0 + m * 16 + l4 * 4 + j;
            float g = gate[grow];
            float wgt = isTrend ? g : (1.f - g);
            float f = wgt / runl[m][j];
#pragma unroll
            for (int ne = 0; ne < 4; ne++)
                outp[(size_t)grow * 2048 + ocol + h * 64 + ne * 16 + l16] =
                    f2bf(oacc[m][ne][j] * f);
        }
    }
}

// ---------------- launch ----------------

extern "C" void kernel_launch(void* const* d_in, const int* in_sizes, int n_in,
                              void* d_out, int out_size, void* d_ws, size_t ws_size,
                              hipStream_t stream) {
    (void)in_sizes; (void)n_in; (void)out_size; (void)ws_size;
    const float* trend  = (const float*)d_in[0];
    const float* detail = (const float*)d_in[1];
    const float* tproto = (const float*)d_in[2];
    const float* dproto = (const float*)d_in[3];
    const float* t_Wq = (const float*)d_in[4];
    const float* t_bq = (const float*)d_in[5];
    const float* t_Wk = (const float*)d_in[6];
    const float* t_bk = (const float*)d_in[7];
    const float* t_Wv = (const float*)d_in[8];
    const float* t_bv = (const float*)d_in[9];
    const float* t_Wo = (const float*)d_in[10];
    const float* t_bo = (const float*)d_in[11];
    const float* d_Wq = (const float*)d_in[12];
    const float* d_bq = (const float*)d_in[13];
    const float* d_Wk = (const float*)d_in[14];
    const float* d_bk = (const float*)d_in[15];
    const float* d_Wv = (const float*)d_in[16];
    const float* d_bv = (const float*)d_in[17];
    const float* d_Wo = (const float*)d_in[18];
    const float* d_bo = (const float*)d_in[19];
    const float* g_W1 = (const float*)d_in[20];
    const float* g_b1 = (const float*)d_in[21];
    const float* g_W2 = (const float*)d_in[22];
    const float* g_b2 = (const float*)d_in[23];

    char* w = (char*)d_ws;
    auto alloc = [&](size_t bytes) {
        char* p = w;
        w += (bytes + 255) & ~(size_t)255;
        return p;
    };
    u16* xcomb  = (u16*)alloc(4096ull * 2048 * 2);
    u16* pt     = (u16*)alloc(1024ull * 4096 * 2);
    u16* pd     = (u16*)alloc(1024ull * 4096 * 2);
    u16* WqTt   = (u16*)alloc(1024ull * 1024 * 2);
    u16* WqTd   = (u16*)alloc(1024ull * 1024 * 2);
    u16* WkvTt  = (u16*)alloc(2048ull * 4096 * 2);
    u16* WkvTd  = (u16*)alloc(2048ull * 4096 * 2);
    u16* WoT    = (u16*)alloc(4096ull * 2048 * 2);
    u16* W1T    = (u16*)alloc(1024ull * 2048 * 2);
    u16* Qt     = (u16*)alloc(4096ull * 1024 * 2);
    u16* Qd     = (u16*)alloc(4096ull * 1024 * 2);
    u16* KVt    = (u16*)alloc(1024ull * 2048 * 2);
    u16* KVd    = (u16*)alloc(1024ull * 2048 * 2);
    u16* VtT    = (u16*)alloc(1024ull * 1024 * 2);
    u16* VdT    = (u16*)alloc(1024ull * 1024 * 2);
    u16* hbuf   = (u16*)alloc(4096ull * 1024 * 2);
    float* gateb = (float*)alloc(4096ull * 4);
    u16* attnc  = (u16*)alloc(4096ull * 2048 * 2);

    dim3 tb(32, 8);

    // 1. converts (+ zero proto pad rows 1000..1023)
    k_build_xcomb<<<8192, 256, 0, stream>>>(trend, detail, xcomb);
    k_convert<<<4000, 256, 0, stream>>>(tproto, pt, 1024000);
    k_convert<<<4000, 256, 0, stream>>>(dproto, pd, 1024000);
    hipMemsetAsync(pt + 1000ull * 4096, 0, 24ull * 4096 * 2, stream);
    hipMemsetAsync(pd + 1000ull * 4096, 0, 24ull * 4096 * 2, stream);

    // 2. weight transposes
    k_transpose_f2b<<<dim3(32, 32), tb, 0, stream>>>(t_Wq, WqTt, 1024, 1024, 1024);
    k_transpose_f2b<<<dim3(32, 32), tb, 0, stream>>>(d_Wq, WqTd, 1024, 1024, 1024);
    k_transpose_f2b<<<dim3(32, 128), tb, 0, stream>>>(t_Wk, WkvTt, 4096, 1024, 4096);
    k_transpose_f2b<<<dim3(32, 128), tb, 0, stream>>>(t_Wv, WkvTt + 1024ull * 4096, 4096, 1024, 4096);
    k_transpose_f2b<<<dim3(32, 128), tb, 0, stream>>>(d_Wk, WkvTd, 4096, 1024, 4096);
    k_transpose_f2b<<<dim3(32, 128), tb, 0, stream>>>(d_Wv, WkvTd + 1024ull * 4096, 4096, 1024, 4096);
    k_transpose_f2b<<<dim3(128, 32), tb, 0, stream>>>(t_Wo, WoT, 1024, 4096, 2048);
    k_transpose_f2b<<<dim3(128, 32), tb, 0, stream>>>(d_Wo, WoT + 1024, 1024, 4096, 2048);
    k_transpose_f2b<<<dim3(32, 64), tb, 0, stream>>>(g_W1, W1T, 2048, 1024, 2048);

    // 3. fused projections: z0 = gate hidden (RELU), z1 = Qt, z2 = Qd
    {
        GemmArgs ga = {};
        ga.A[0] = xcomb;        ga.B[0] = W1T;  ga.o[0] = hbuf;
        ga.bias1[0] = g_b1;     ga.K[0] = 2048; ga.lda[0] = 2048; ga.ldc[0] = 1024;
        ga.mode[0] = MODE_BF16_RELU;
        ga.A[1] = xcomb;        ga.B[1] = WqTt; ga.o[1] = Qt;
        ga.bias1[1] = t_bq;     ga.K[1] = 1024; ga.lda[1] = 2048; ga.ldc[1] = 1024;
        ga.mode[1] = MODE_BF16;
        ga.A[2] = xcomb + 1024; ga.B[2] = WqTd; ga.o[2] = Qd;
        ga.bias1[2] = d_bq;     ga.K[2] = 1024; ga.lda[2] = 2048; ga.ldc[2] = 1024;
        ga.mode[2] = MODE_BF16;
        k_gemm128<<<dim3(8, 32, 3), 256, 0, stream>>>(ga);
    }
    k_gate<<<1024, 256, 0, stream>>>(hbuf, g_W2, g_b2, gateb);

    // 4. K|V projections (M=1024 padded, N=2048, K=4096), z-batched
    {
        GemmArgs ga = {};
        ga.A[0] = pt; ga.B[0] = WkvTt; ga.o[0] = KVt;
        ga.bias1[0] = t_bk; ga.bias2[0] = t_bv;
        ga.K[0] = 4096; ga.lda[0] = 4096; ga.ldc[0] = 2048; ga.mode[0] = MODE_BF16;
        ga.A[1] = pd; ga.B[1] = WkvTd; ga.o[1] = KVd;
        ga.bias1[1] = d_bk; ga.bias2[1] = d_bv;
        ga.K[1] = 4096; ga.lda[1] = 4096; ga.ldc[1] = 2048; ga.mode[1] = MODE_BF16;
        k_gemm128<<<dim3(16, 8, 2), 256, 0, stream>>>(ga);
    }

    // 5. V transposes -> [h*64+e][s]
    k_transpose_b2b<<<dim3(32, 32), tb, 0, stream>>>(KVt + 1024, 2048, VtT, 1024, 1024, 1024);
    k_transpose_b2b<<<dim3(32, 32), tb, 0, stream>>>(KVd + 1024, 2048, VdT, 1024, 1024, 1024);

    // 6. fused attention, both streams in one dispatch
    k_attn<<<dim3(4, 128, 2), 256, 0, stream>>>(Qt, Qd, KVt, KVd, 2048, VtT, VdT,
                                                gateb, attnc);

    // 7. final gated output GEMM -> d_out (f32), 8-phase 256^2
    k_gemm256g<<<dim3(16, 16), 512, 0, stream>>>(attnc, 2048, WoT, 2048, 2048,
                                                 (float*)d_out, 4096, t_bo, d_bo, gateb);
}

// Round 4
// 610.626 us; speedup vs baseline: 1.8090x; 1.0595x over previous
//
#include <hip/hip_runtime.h>

typedef unsigned short u16;
typedef unsigned int u32;
typedef __attribute__((ext_vector_type(4))) u16 u16x4;
typedef __attribute__((ext_vector_type(8))) u16 u16x8;
typedef __attribute__((ext_vector_type(2))) u32 u32x2;
typedef __attribute__((ext_vector_type(4))) u32 u32x4;
typedef __attribute__((ext_vector_type(4))) float f32x4;
typedef __attribute__((ext_vector_type(16))) float f32x16;
typedef __attribute__((ext_vector_type(8))) __bf16 bf16x8;

#define DEV static __device__ __forceinline__

DEV u16 f2bf(float f) {
    u32 u = __builtin_bit_cast(u32, f);
    return (u16)((u + 0x7FFFu + ((u >> 16) & 1u)) >> 16);
}
DEV float bf2f(u16 h) { return __builtin_bit_cast(float, (u32)h << 16); }
DEV u16 f2bfc(float f) { return __builtin_bit_cast(u16, (__bf16)f); }   // fptrunc RNE
DEV u32 pk2(float lo, float hi) { return (u32)f2bfc(lo) | ((u32)f2bfc(hi) << 16); }

DEV f32x4 mfma16(u16x8 a, u16x8 b, f32x4 c) {
    return __builtin_amdgcn_mfma_f32_16x16x32_bf16(
        __builtin_bit_cast(bf16x8, a), __builtin_bit_cast(bf16x8, b), c, 0, 0, 0);
}
DEV f32x16 mfma32(u16x8 a, u16x8 b, f32x16 c) {
    return __builtin_amdgcn_mfma_f32_32x32x16_bf16(
        __builtin_bit_cast(bf16x8, a), __builtin_bit_cast(bf16x8, b), c, 0, 0, 0);
}

// exchange: new_a = lane<32 ? a : b[lane-32];  new_b = lane<32 ? a[lane+32] : b
DEV void swap32(u32 a, u32 b, u32& ra, u32& rb) {
#if __has_builtin(__builtin_amdgcn_permlane32_swap)
    u32x2 r = __builtin_amdgcn_permlane32_swap(a, b, false, false);
    ra = r[0]; rb = r[1];
#else
    u32 bx = (u32)__shfl_xor((int)b, 32);
    u32 ax = (u32)__shfl_xor((int)a, 32);
    bool hi = (threadIdx.x & 32) != 0;
    ra = hi ? bx : a;
    rb = hi ? b : ax;
#endif
}

// async global->LDS, 16B/lane
DEV void gload16(const void* g, void* l) {
    __builtin_amdgcn_global_load_lds(
        (const __attribute__((address_space(1))) void*)g,
        (__attribute__((address_space(3))) void*)l, 16, 0, 0);
}

// ---------------- elementwise converts ----------------

__global__ __launch_bounds__(256) void k_build_xcomb(
    const float* __restrict__ tr, const float* __restrict__ de, u16* __restrict__ out) {
    int i = blockIdx.x * 256 + threadIdx.x;
    int m = i >> 9;
    int c = (i & 511) * 4;
    const float* src = (c < 1024) ? (tr + (size_t)m * 1024 + c)
                                  : (de + (size_t)m * 1024 + (c - 1024));
    f32x4 v = *(const f32x4*)src;
    u16x4 o = { f2bf(v[0]), f2bf(v[1]), f2bf(v[2]), f2bf(v[3]) };
    *(u16x4*)(out + (size_t)m * 2048 + c) = o;
}

__global__ __launch_bounds__(256) void k_convert(
    const float* __restrict__ in, u16* __restrict__ out, int n4) {
    int i = blockIdx.x * 256 + threadIdx.x;
    if (i >= n4) return;
    f32x4 v = ((const f32x4*)in)[i];
    u16x4 o = { f2bf(v[0]), f2bf(v[1]), f2bf(v[2]), f2bf(v[3]) };
    ((u16x4*)out)[i] = o;
}

// ---------------- transposes ----------------

__global__ void k_transpose_f2b(const float* __restrict__ in, u16* __restrict__ out,
                                int R, int C, int ldo) {
    __shared__ float t[32][33];
    int c0 = blockIdx.x * 32, r0 = blockIdx.y * 32;
    int tx = threadIdx.x, ty = threadIdx.y;   // (32,8)
#pragma unroll
    for (int j = 0; j < 4; j++)
        t[ty + j * 8][tx] = in[(size_t)(r0 + ty + j * 8) * C + c0 + tx];
    __syncthreads();
#pragma unroll
    for (int j = 0; j < 4; j++)
        out[(size_t)(c0 + ty + j * 8) * ldo + r0 + tx] = f2bf(t[tx][ty + j * 8]);
}

__global__ void k_transpose_b2b(const u16* __restrict__ in, int ldi,
                                u16* __restrict__ out, int ldo, int R, int C) {
    __shared__ u16 t[32][33];
    int c0 = blockIdx.x * 32, r0 = blockIdx.y * 32;
    int tx = threadIdx.x, ty = threadIdx.y;
#pragma unroll
    for (int j = 0; j < 4; j++)
        t[ty + j * 8][tx] = in[(size_t)(r0 + ty + j * 8) * ldi + c0 + tx];
    __syncthreads();
#pragma unroll
    for (int j = 0; j < 4; j++)
        out[(size_t)(c0 + ty + j * 8) * ldo + r0 + tx] = t[tx][ty + j * 8];
}

// ---------------- m97-style 128x128 GEMM (z-batched via struct) ----------------
#define MODE_BF16 0
#define MODE_BF16_RELU 1

struct GemmArgs {
    const u16* A[3];
    const u16* B[3];
    u16* o[3];
    const float* bias1[3];
    const float* bias2[3];
    float scale[3];
    int K[3];
    int lda[3];
    int ldc[3];
    int mode[3];
};

__global__ __launch_bounds__(256) void k_gemm128(GemmArgs ga) {
    __shared__ u16 As[128 * 32];
    __shared__ u16 Bs[128 * 32];
    const int z = blockIdx.z;
    const u16* A = ga.A[z];
    const u16* Bt = ga.B[z];
    u16* outp = ga.o[z];
    const float* bias1 = ga.bias1[z];
    const float* bias2 = ga.bias2[z];
    const float scale = ga.scale[z];
    const int K = ga.K[z], lda = ga.lda[z], ldc = ga.ldc[z], mode = ga.mode[z];

    const int tid = threadIdx.x, lane = tid & 63, wid = tid >> 6;
    const int l16 = lane & 15, l4 = lane >> 4;
    const int n0 = blockIdx.x * 128, m0 = blockIdx.y * 128;
    const int wm = (wid >> 1) * 64, wn = (wid & 1) * 64;

    const int srow = wid * 32 + (lane >> 2);
    const int scol = (lane & 3) * 8;
    const u16* gA = A + (size_t)(m0 + srow) * lda + scol;
    const u16* gB = Bt + (size_t)(n0 + srow) * (size_t)K + scol;
    u16* lA = As + wid * 32 * 32;
    u16* lB = Bs + wid * 32 * 32;

    f32x4 acc[4][4] = {};

    for (int k0 = 0; k0 < K; k0 += 32) {
        gload16(gA, lA);
        gload16(gA + (size_t)16 * lda, lA + 16 * 32);
        gload16(gB, lB);
        gload16(gB + (size_t)16 * K, lB + 16 * 32);
        gA += 32;
        gB += 32;
        __syncthreads();
        u16x8 af[4], bfr[4];
#pragma unroll
        for (int m = 0; m < 4; m++) af[m] = *(const u16x8*)&As[(wm + m * 16 + l16) * 32 + l4 * 8];
#pragma unroll
        for (int n = 0; n < 4; n++) bfr[n] = *(const u16x8*)&Bs[(wn + n * 16 + l16) * 32 + l4 * 8];
#pragma unroll
        for (int m = 0; m < 4; m++)
#pragma unroll
            for (int n = 0; n < 4; n++)
                acc[m][n] = mfma16(af[m], bfr[n], acc[m][n]);
        __syncthreads();
    }

#pragma unroll
    for (int m = 0; m < 4; m++) {
#pragma unroll
        for (int n = 0; n < 4; n++) {
            int col = n0 + wn + n * 16 + l16;
#pragma unroll
            for (int j = 0; j < 4; j++) {
                int row = m0 + wm + m * 16 + l4 * 4 + j;
                float v = acc[m][n][j];
                float bb = (bias2 != nullptr && col >= 1024) ? bias2[col - 1024] : bias1[col];
                v = (v + bb) * scale;
                if (mode == MODE_BF16_RELU) v = fmaxf(v, 0.f);
                outp[(size_t)row * ldc + col] = f2bf(v);
            }
        }
    }
}

// ---------------- 256^2 8-phase GEMM, gated f32 epilogue ----------------
__global__ __launch_bounds__(512, 2) void k_gemm256g(
    const u16* __restrict__ A, int ldaE,
    const u16* __restrict__ Bt, int ldbE,
    int K,
    float* __restrict__ C, int ldcE,
    const float* __restrict__ bias1, const float* __restrict__ bias2,
    const float* __restrict__ gate) {
    __shared__ __attribute__((aligned(16))) u16 sm[2 * 32768];  // 128 KiB
    char* smc = (char*)sm;

    const int tid = threadIdx.x, lane = tid & 63, wid = tid >> 6;
    const int l16 = lane & 15, l4 = lane >> 4;
    const int wm = (wid >> 2) * 128;
    const int wn = (wid & 3) * 64;
    const int m0 = blockIdx.y * 256, n0 = blockIdx.x * 256;

    const int p0 = wid * 1024 + lane * 16;
    const int p1 = p0 + 8192;
    const int rr0 = p0 >> 7, rr1 = p1 >> 7;
    const int cb0 = (p0 & 127) ^ ((rr0 & 7) << 4);
    const int cb1 = (p1 & 127) ^ ((rr1 & 7) << 4);
    const size_t ldaB = (size_t)ldaE * 2, ldbB = (size_t)ldbE * 2;
    const char* Ab = (const char*)A;
    const char* Bb = (const char*)Bt;
    const size_t aOff0 = (size_t)(m0 + rr0) * ldaB + cb0;
    const size_t aOff1 = (size_t)(m0 + rr1) * ldaB + cb1;
    const size_t bOff0 = (size_t)(n0 + rr0) * ldbB + cb0;
    const size_t bOff1 = (size_t)(n0 + rr1) * ldbB + cb1;

    auto stageA = [&](int T, int h) {
        size_t tOff = (size_t)T * 128 + (size_t)h * 128 * ldaB;
        char* d = smc + (T & 1) * 65536 + h * 16384 + wid * 1024;
        gload16(Ab + aOff0 + tOff, d);
        gload16(Ab + aOff1 + tOff, d + 8192);
    };
    auto stageB = [&](int T, int h) {
        size_t tOff = (size_t)T * 128 + (size_t)h * 128 * ldbB;
        char* d = smc + (T & 1) * 65536 + 32768 + h * 16384 + wid * 1024;
        gload16(Bb + bOff0 + tOff, d);
        gload16(Bb + bOff1 + tOff, d + 8192);
    };
    auto readA = [&](int buf, int mf, int kc) -> u16x8 {
        int row = wm + mf * 16 + l16;
        int cb = (kc * 64 + l4 * 16) ^ ((l16 & 7) << 4);
        return *(const u16x8*)(smc + buf * 65536 + row * 128 + cb);
    };
    auto readB = [&](int buf, int nf, int kc) -> u16x8 {
        int row = wn + nf * 16 + l16;
        int cb = (kc * 64 + l4 * 16) ^ ((l16 & 7) << 4);
        return *(const u16x8*)(smc + buf * 65536 + 32768 + row * 128 + cb);
    };

    f32x4 acc[8][4] = {};
    const int NT = K >> 6;

    stageA(0, 0); stageA(0, 1);
    stageB(0, 0); stageB(0, 1);
    stageB(1, 0); stageB(1, 1);
    asm volatile("s_waitcnt vmcnt(4)" ::: "memory");
    __builtin_amdgcn_s_barrier();

    for (int t = 0; t < NT; ++t) {
        const int buf = t & 1;
        u16x8 bfr[4][2];
#pragma unroll
        for (int q = 0; q < 4; ++q) {
            u16x8 af[2][2];
            if (q == 0) {
#pragma unroll
                for (int nf = 0; nf < 4; nf++)
#pragma unroll
                    for (int kc = 0; kc < 2; kc++) bfr[nf][kc] = readB(buf, nf, kc);
            }
#pragma unroll
            for (int im = 0; im < 2; im++)
#pragma unroll
                for (int kc = 0; kc < 2; kc++) af[im][kc] = readA(buf, 2 * q + im, kc);

            if (q == 0) { if (t + 1 < NT) stageA(t + 1, 0); }
            else if (q == 1) { if (t + 1 < NT) stageA(t + 1, 1); }
            else if (q == 2) { if (t + 2 < NT) stageB(t + 2, 0); }
            else { if (t + 2 < NT) stageB(t + 2, 1); }

            asm volatile("" ::: "memory");
            __builtin_amdgcn_s_barrier();
            __builtin_amdgcn_s_setprio(1);
#pragma unroll
            for (int im = 0; im < 2; im++)
#pragma unroll
                for (int nf = 0; nf < 4; nf++)
#pragma unroll
                    for (int kc = 0; kc < 2; kc++)
                        acc[2 * q + im][nf] = mfma16(af[im][kc], bfr[nf][kc], acc[2 * q + im][nf]);
            __builtin_amdgcn_s_setprio(0);
            asm volatile("" ::: "memory");
            if (q == 3) {
                if (t + 2 < NT) asm volatile("s_waitcnt vmcnt(4)" ::: "memory");
                else            asm volatile("s_waitcnt vmcnt(0)" ::: "memory");
            }
            __builtin_amdgcn_s_barrier();
        }
    }

#pragma unroll
    for (int mf = 0; mf < 8; mf++) {
#pragma unroll
        for (int j = 0; j < 4; j++) {
            int row = m0 + wm + mf * 16 + l4 * 4 + j;
            float g = gate[row];
#pragma unroll
            for (int nf = 0; nf < 4; nf++) {
                int col = n0 + wn + nf * 16 + l16;
                C[(size_t)row * ldcE + col] =
                    acc[mf][nf][j] + g * bias1[col] + (1.f - g) * bias2[col];
            }
        }
    }
}

// ---------------- gate GEMV: sigmoid(h @ W2 + b2) ----------------
__global__ __launch_bounds__(256) void k_gate(const u16* __restrict__ h,
                                              const float* __restrict__ W2,
                                              const float* __restrict__ b2,
                                              float* __restrict__ gate) {
    int row = blockIdx.x * 4 + (threadIdx.x >> 6);
    int lane = threadIdx.x & 63;
    const u16* hp = h + (size_t)row * 1024 + lane * 16;
    u16x8 a = *(const u16x8*)hp;
    u16x8 b = *(const u16x8*)(hp + 8);
    const f32x4* wp = (const f32x4*)(W2 + lane * 16);
    f32x4 w0 = wp[0], w1 = wp[1], w2 = wp[2], w3 = wp[3];
    float s = 0.f;
#pragma unroll
    for (int i = 0; i < 4; i++) {
        s += bf2f(a[i]) * w0[i];
        s += bf2f(a[4 + i]) * w1[i];
        s += bf2f(b[i]) * w2[i];
        s += bf2f(b[4 + i]) * w3[i];
    }
#pragma unroll
    for (int d = 1; d < 64; d <<= 1) s += __shfl_xor(s, d);
    if (lane == 0) gate[row] = 1.f / (1.f + __expf(-(s + b2[0])));
}

// ---------------- fused flash cross-attention, swapped-QK in-register ---------
// Per wave: 32 q-rows, all 1024 (padded) prototypes in 32 s-tiles of 32.
// QK^T computed swapped (A=K, B=Q) -> lane holds P^T[:, q=lane&31] (16 regs).
// Softmax in-register; P->bf16 via pk2 + permlane32_swap; PV as O^T = V^T @ P^T.
// Q was pre-scaled by 1/8 in its projection GEMM. No LDS, no barriers.
__global__ __launch_bounds__(256) void k_attn(
    const u16* __restrict__ Q0, const u16* __restrict__ Q1,
    const u16* __restrict__ KV0, const u16* __restrict__ KV1,
    const u16* __restrict__ Vt0, const u16* __restrict__ Vt1,
    const float* __restrict__ gate,
    u16* __restrict__ outp) {
    const int z = blockIdx.z;
    const u16* Q = z ? Q1 : Q0;
    const u16* Kb = z ? KV1 : KV0;   // [1024 s][2048], K at col h*64
    const u16* Vt = z ? Vt1 : Vt0;   // [h*64+e][1024 s]
    const int ocol = z * 1024;

    const int tid = threadIdx.x, lane = tid & 63, wid = tid >> 6;
    const int l31 = lane & 31, hi = lane >> 5;
    const int bh = blockIdx.y;
    const int b = bh >> 4, h = bh & 15;
    const int row0 = b * 512 + blockIdx.x * 128 + wid * 32;

    // Q fragments (B-operand): col=q=row0+l31, k=d = kc*16 + hi*8 + j
    u16x8 qf[4];
    const u16* qp = Q + (size_t)(row0 + l31) * 1024 + h * 64 + hi * 8;
#pragma unroll
    for (int kc = 0; kc < 4; kc++) qf[kc] = *(const u16x8*)(qp + kc * 16);

    const u16* kp = Kb + (size_t)l31 * 2048 + h * 64 + hi * 8;
    const u16* vp = Vt + (size_t)(h * 64 + l31) * 1024 + hi * 8;

    f32x16 oacc0 = {}, oacc1 = {};
    float runm = -3.0e38f, runl = 0.f;

    for (int st = 0; st < 32; ++st) {
        const int s0 = st * 32;
        const u16* kt = kp + (size_t)s0 * 2048;
        u16x8 kf0 = *(const u16x8*)(kt);
        u16x8 kf1 = *(const u16x8*)(kt + 16);
        u16x8 kf2 = *(const u16x8*)(kt + 32);
        u16x8 kf3 = *(const u16x8*)(kt + 48);
        f32x16 p = {};
        p = mfma32(kf0, qf[0], p);
        p = mfma32(kf1, qf[1], p);
        p = mfma32(kf2, qf[2], p);
        p = mfma32(kf3, qf[3], p);
        // V fragments (issue early; consumed after softmax)
        u16x8 vf00 = *(const u16x8*)(vp + s0);
        u16x8 vf01 = *(const u16x8*)(vp + s0 + 16);
        u16x8 vf10 = *(const u16x8*)(vp + 32 * 1024 + s0);
        u16x8 vf11 = *(const u16x8*)(vp + 32 * 1024 + s0 + 16);

        if (st == 31) {      // s = 992 + srow; srow>=8 (i.e. reg>=4) is s>=1000
#pragma unroll
            for (int r = 4; r < 16; r++) p[r] = -3.0e38f;
        }

        // online softmax: lane's 16 regs = 16 s-values of one q-row (half);
        // cross-half combine via lane^32.
        float pm = p[0];
#pragma unroll
        for (int r = 1; r < 16; r++) pm = fmaxf(pm, p[r]);
        pm = fmaxf(pm, __shfl_xor(pm, 32));
        if (__any(pm > runm + 8.f)) {      // T13 defer-max, THR=8
            float nm = fmaxf(runm, pm);
            float corr = __expf(runm - nm);
            runm = nm;
            runl *= corr;
            oacc0 *= corr;
            oacc1 *= corr;
        }
        float ts = 0.f;
#pragma unroll
        for (int r = 0; r < 16; r++) {
            float e = __expf(p[r] - runm);
            p[r] = e;
            ts += e;
        }
        runl += ts + __shfl_xor(ts, 32);

        // pack P^T into PV B-fragments (k = s_local = hi*8+j within 16-chunk)
        u16x8 pw[2];
#pragma unroll
        for (int ks = 0; ks < 2; ks++) {
            u32 a0 = pk2(p[8 * ks + 0], p[8 * ks + 1]);
            u32 b0 = pk2(p[8 * ks + 4], p[8 * ks + 5]);
            u32 a1 = pk2(p[8 * ks + 2], p[8 * ks + 3]);
            u32 b1 = pk2(p[8 * ks + 6], p[8 * ks + 7]);
            u32 w0, w1, w2, w3;
            swap32(a0, b0, w0, w2);
            swap32(a1, b1, w1, w3);
            u32x4 wv = { w0, w1, w2, w3 };
            pw[ks] = __builtin_bit_cast(u16x8, wv);
        }

        oacc0 = mfma32(vf00, pw[0], oacc0);
        oacc0 = mfma32(vf01, pw[1], oacc0);
        oacc1 = mfma32(vf10, pw[0], oacc1);
        oacc1 = mfma32(vf11, pw[1], oacc1);
    }

    // epilogue: O[q][d] = oacc^T, scaled by gate-weight / runl
    int grow = row0 + l31;
    float g = gate[grow];
    float wgt = z ? (1.f - g) : g;
    float f = wgt / runl;
    u16* op = outp + (size_t)grow * 2048 + ocol + h * 64 + hi * 4;
#pragma unroll
    for (int dh = 0; dh < 2; dh++) {
#pragma unroll
        for (int quad = 0; quad < 4; quad++) {
            u16x4 s;
#pragma unroll
            for (int j = 0; j < 4; j++) {
                float v = (dh ? oacc1[quad * 4 + j] : oacc0[quad * 4 + j]) * f;
                s[j] = f2bfc(v);
            }
            *(u16x4*)(op + dh * 32 + quad * 8) = s;
        }
    }
}

// ---------------- launch ----------------

extern "C" void kernel_launch(void* const* d_in, const int* in_sizes, int n_in,
                              void* d_out, int out_size, void* d_ws, size_t ws_size,
                              hipStream_t stream) {
    (void)in_sizes; (void)n_in; (void)out_size; (void)ws_size;
    const float* trend  = (const float*)d_in[0];
    const float* detail = (const float*)d_in[1];
    const float* tproto = (const float*)d_in[2];
    const float* dproto = (const float*)d_in[3];
    const float* t_Wq = (const float*)d_in[4];
    const float* t_bq = (const float*)d_in[5];
    const float* t_Wk = (const float*)d_in[6];
    const float* t_bk = (const float*)d_in[7];
    const float* t_Wv = (const float*)d_in[8];
    const float* t_bv = (const float*)d_in[9];
    const float* t_Wo = (const float*)d_in[10];
    const float* t_bo = (const float*)d_in[11];
    const float* d_Wq = (const float*)d_in[12];
    const float* d_bq = (const float*)d_in[13];
    const float* d_Wk = (const float*)d_in[14];
    const float* d_bk = (const float*)d_in[15];
    const float* d_Wv = (const float*)d_in[16];
    const float* d_bv = (const float*)d_in[17];
    const float* d_Wo = (const float*)d_in[18];
    const float* d_bo = (const float*)d_in[19];
    const float* g_W1 = (const float*)d_in[20];
    const float* g_b1 = (const float*)d_in[21];
    const float* g_W2 = (const float*)d_in[22];
    const float* g_b2 = (const float*)d_in[23];

    char* w = (char*)d_ws;
    auto alloc = [&](size_t bytes) {
        char* p = w;
        w += (bytes + 255) & ~(size_t)255;
        return p;
    };
    u16* xcomb  = (u16*)alloc(4096ull * 2048 * 2);
    u16* pt     = (u16*)alloc(1024ull * 4096 * 2);
    u16* pd     = (u16*)alloc(1024ull * 4096 * 2);
    u16* WqTt   = (u16*)alloc(1024ull * 1024 * 2);
    u16* WqTd   = (u16*)alloc(1024ull * 1024 * 2);
    u16* WkvTt  = (u16*)alloc(2048ull * 4096 * 2);
    u16* WkvTd  = (u16*)alloc(2048ull * 4096 * 2);
    u16* WoT    = (u16*)alloc(4096ull * 2048 * 2);
    u16* W1T    = (u16*)alloc(1024ull * 2048 * 2);
    u16* Qt     = (u16*)alloc(4096ull * 1024 * 2);
    u16* Qd     = (u16*)alloc(4096ull * 1024 * 2);
    u16* KVt    = (u16*)alloc(1024ull * 2048 * 2);
    u16* KVd    = (u16*)alloc(1024ull * 2048 * 2);
    u16* VtT    = (u16*)alloc(1024ull * 1024 * 2);
    u16* VdT    = (u16*)alloc(1024ull * 1024 * 2);
    u16* hbuf   = (u16*)alloc(4096ull * 1024 * 2);
    float* gateb = (float*)alloc(4096ull * 4);
    u16* attnc  = (u16*)alloc(4096ull * 2048 * 2);

    dim3 tb(32, 8);

    // 1. converts (+ zero proto pad rows 1000..1023)
    k_build_xcomb<<<8192, 256, 0, stream>>>(trend, detail, xcomb);
    k_convert<<<4000, 256, 0, stream>>>(tproto, pt, 1024000);
    k_convert<<<4000, 256, 0, stream>>>(dproto, pd, 1024000);
    hipMemsetAsync(pt + 1000ull * 4096, 0, 24ull * 4096 * 2, stream);
    hipMemsetAsync(pd + 1000ull * 4096, 0, 24ull * 4096 * 2, stream);

    // 2. weight transposes
    k_transpose_f2b<<<dim3(32, 32), tb, 0, stream>>>(t_Wq, WqTt, 1024, 1024, 1024);
    k_transpose_f2b<<<dim3(32, 32), tb, 0, stream>>>(d_Wq, WqTd, 1024, 1024, 1024);
    k_transpose_f2b<<<dim3(32, 128), tb, 0, stream>>>(t_Wk, WkvTt, 4096, 1024, 4096);
    k_transpose_f2b<<<dim3(32, 128), tb, 0, stream>>>(t_Wv, WkvTt + 1024ull * 4096, 4096, 1024, 4096);
    k_transpose_f2b<<<dim3(32, 128), tb, 0, stream>>>(d_Wk, WkvTd, 4096, 1024, 4096);
    k_transpose_f2b<<<dim3(32, 128), tb, 0, stream>>>(d_Wv, WkvTd + 1024ull * 4096, 4096, 1024, 4096);
    k_transpose_f2b<<<dim3(128, 32), tb, 0, stream>>>(t_Wo, WoT, 1024, 4096, 2048);
    k_transpose_f2b<<<dim3(128, 32), tb, 0, stream>>>(d_Wo, WoT + 1024, 1024, 4096, 2048);
    k_transpose_f2b<<<dim3(32, 64), tb, 0, stream>>>(g_W1, W1T, 2048, 1024, 2048);

    // 3. fused projections: z0 = gate hidden (RELU), z1 = Qt (x1/8), z2 = Qd (x1/8)
    {
        GemmArgs ga = {};
        ga.A[0] = xcomb;        ga.B[0] = W1T;  ga.o[0] = hbuf;
        ga.bias1[0] = g_b1;     ga.K[0] = 2048; ga.lda[0] = 2048; ga.ldc[0] = 1024;
        ga.mode[0] = MODE_BF16_RELU; ga.scale[0] = 1.f;
        ga.A[1] = xcomb;        ga.B[1] = WqTt; ga.o[1] = Qt;
        ga.bias1[1] = t_bq;     ga.K[1] = 1024; ga.lda[1] = 2048; ga.ldc[1] = 1024;
        ga.mode[1] = MODE_BF16; ga.scale[1] = 0.125f;
        ga.A[2] = xcomb + 1024; ga.B[2] = WqTd; ga.o[2] = Qd;
        ga.bias1[2] = d_bq;     ga.K[2] = 1024; ga.lda[2] = 2048; ga.ldc[2] = 1024;
        ga.mode[2] = MODE_BF16; ga.scale[2] = 0.125f;
        k_gemm128<<<dim3(8, 32, 3), 256, 0, stream>>>(ga);
    }
    k_gate<<<1024, 256, 0, stream>>>(hbuf, g_W2, g_b2, gateb);

    // 4. K|V projections (M=1024 padded, N=2048, K=4096), z-batched
    {
        GemmArgs ga = {};
        ga.A[0] = pt; ga.B[0] = WkvTt; ga.o[0] = KVt;
        ga.bias1[0] = t_bk; ga.bias2[0] = t_bv; ga.scale[0] = 1.f;
        ga.K[0] = 4096; ga.lda[0] = 4096; ga.ldc[0] = 2048; ga.mode[0] = MODE_BF16;
        ga.A[1] = pd; ga.B[1] = WkvTd; ga.o[1] = KVd;
        ga.bias1[1] = d_bk; ga.bias2[1] = d_bv; ga.scale[1] = 1.f;
        ga.K[1] = 4096; ga.lda[1] = 4096; ga.ldc[1] = 2048; ga.mode[1] = MODE_BF16;
        k_gemm128<<<dim3(16, 8, 2), 256, 0, stream>>>(ga);
    }

    // 5. V transposes -> [h*64+e][s]
    k_transpose_b2b<<<dim3(32, 32), tb, 0, stream>>>(KVt + 1024, 2048, VtT, 1024, 1024, 1024);
    k_transpose_b2b<<<dim3(32, 32), tb, 0, stream>>>(KVd + 1024, 2048, VdT, 1024, 1024, 1024);

    // 6. fused attention, both streams, no LDS
    k_attn<<<dim3(4, 128, 2), 256, 0, stream>>>(Qt, Qd, KVt, KVd, VtT, VdT,
                                                gateb, attnc);

    // 7. final gated output GEMM -> d_out (f32), 8-phase 256^2
    k_gemm256g<<<dim3(16, 16), 512, 0, stream>>>(attnc, 2048, WoT, 2048, 2048,
                                                 (float*)d_out, 4096, t_bo, d_bo, gateb);
}